// Round 1
// baseline (3183.041 us; speedup 1.0000x reference)
//
#include <hip/hip_runtime.h>
#include <cstddef>

#define HH 128
#define WW2 128
#define HWSZ (HH*WW2)
#define CCH 256

// ---------------- fold: Wf[ci][k][co] = l1s*l1w (+ center: l2s*l2w); biasf = l1b+l2b
__global__ __launch_bounds__(256) void k_fold(const float* __restrict__ l1w, const float* __restrict__ l1s,
                                              const float* __restrict__ l1b, const float* __restrict__ l2w,
                                              const float* __restrict__ l2s, const float* __restrict__ l2b,
                                              float* __restrict__ Wf, float* __restrict__ biasf) {
    int idx = blockIdx.x * 256 + threadIdx.x;
    if (idx < 2304 * 256) {
        int co = idx & 255;
        int i2 = idx >> 8;           // 0..2303 = ci*9+k
        int ci = i2 / 9;
        int k  = i2 - ci * 9;
        float w = l1s[co] * l1w[co * 2304 + ci * 9 + k];
        if (k == 4) w += l2s[co] * l2w[co * 256 + ci];
        Wf[i2 * 256 + co] = w;
    }
    if (idx < 256) biasf[idx] = l1b[idx] + l2b[idx];
}

// ---------------- fused 3x3 conv (local path): 64co x (16 rows x 8 cols) tile
__global__ __launch_bounds__(256) void k_conv3(const float* __restrict__ x, const float* __restrict__ Wf,
                                               const float* __restrict__ biasf, float* __restrict__ outp) {
    __shared__ __align__(16) float xs[8][18][12];
    __shared__ __align__(16) float wsm[8][9][64];
    int t = threadIdx.x;
    int bid = blockIdx.x;
    int cb = bid & 3;
    int tile = bid >> 2;
    int tx = tile & 15;
    int ty = (tile >> 4) & 7;
    int b = tile >> 7;
    int x0 = tx * 8, y0 = ty * 16;
    int cg = t >> 4;   // 0..15 (4 co each)
    int r  = t & 15;   // row within tile

    float acc[4][8];
#pragma unroll
    for (int c = 0; c < 4; ++c)
#pragma unroll
        for (int j = 0; j < 8; ++j) acc[c][j] = 0.f;

    const float* xb = x + (size_t)b * CCH * HWSZ;

    for (int cc = 0; cc < 32; ++cc) {
        __syncthreads();
        for (int i = t; i < 1728; i += 256) {  // 8ci x 18r x 12c
            int ci = i / 216; int rem = i - ci * 216;
            int rr = rem / 12; int c = rem - rr * 12;
            int gy = y0 - 1 + rr; int gx = x0 - 1 + c;
            float v = 0.f;
            if (c < 10 && gy >= 0 && gy < 128 && gx >= 0 && gx < 128)
                v = xb[(size_t)(cc * 8 + ci) * HWSZ + gy * 128 + gx];
            xs[ci][rr][c] = v;
        }
        for (int i = t; i < 4608; i += 256) {  // 8ci x 9k x 64co
            int ci = i / 576; int rem = i - ci * 576;
            int k = rem >> 6; int co = rem & 63;
            wsm[ci][k][co] = Wf[(size_t)((cc * 8 + ci) * 9 + k) * 256 + cb * 64 + co];
        }
        __syncthreads();
#pragma unroll
        for (int ci = 0; ci < 8; ++ci) {
            float xf[3][12];
#pragma unroll
            for (int dy = 0; dy < 3; ++dy) {
#pragma unroll
                for (int m = 0; m < 3; ++m) {
                    float4 tmp = *(const float4*)&xs[ci][r + dy][m * 4];
                    xf[dy][m * 4 + 0] = tmp.x; xf[dy][m * 4 + 1] = tmp.y;
                    xf[dy][m * 4 + 2] = tmp.z; xf[dy][m * 4 + 3] = tmp.w;
                }
            }
#pragma unroll
            for (int dy = 0; dy < 3; ++dy) {
#pragma unroll
                for (int dx = 0; dx < 3; ++dx) {
                    float4 w = *(const float4*)&wsm[ci][dy * 3 + dx][cg * 4];
#pragma unroll
                    for (int j = 0; j < 8; ++j) {
                        float xv = xf[dy][j + dx];
                        acc[0][j] += w.x * xv;
                        acc[1][j] += w.y * xv;
                        acc[2][j] += w.z * xv;
                        acc[3][j] += w.w * xv;
                    }
                }
            }
        }
    }
    int y = y0 + r;
#pragma unroll
    for (int c = 0; c < 4; ++c) {
        int co = cb * 64 + cg * 4 + c;
        float bv = biasf[co];
        float* op = outp + ((size_t)(b * CCH + co)) * HWSZ + y * 128 + x0;
        float4 o0 = make_float4(acc[c][0] + bv, acc[c][1] + bv, acc[c][2] + bv, acc[c][3] + bv);
        float4 o1 = make_float4(acc[c][4] + bv, acc[c][5] + bv, acc[c][6] + bv, acc[c][7] + bv);
        *(float4*)op = o0;
        *(float4*)(op + 4) = o1;
    }
}

// ---------------- fused qkv + window attention: one WG per 8x8 window
__global__ __launch_bounds__(256) void k_attn(const float* __restrict__ x, const float* __restrict__ qkvw,
                                              const float* __restrict__ bt, float* __restrict__ attnout) {
    __shared__ __align__(16) float qkvb[48][64];   // q:0-15, k:16-31, v:32-47 (rows) x token
    int t = threadIdx.x;
    int wv = __builtin_amdgcn_readfirstlane(t >> 6);
    int lane = t & 63;
    int widx = blockIdx.x;
    int b = widx >> 8;
    int rem = widx & 255;
    int hy = rem >> 4, wx = rem & 15;
    int y0 = hy * 8, x0 = wx * 8;
    int ty = lane >> 3, px_ = lane & 7;
    const float* xb = x + (size_t)b * CCH * HWSZ + (y0 + ty) * 128 + (x0 + px_);
    int irow = wv * 16 + (lane & 15);   // attention row this lane helps with
    int jg = lane >> 4;                 // j-quarter 0..3
    int iy = irow >> 3, ix = irow & 7;

    for (int h = 0; h < 16; ++h) {
        __syncthreads();
        // ---- qkv for this head: wave wv computes rows 12*wv .. 12*wv+11, lane = token
        float acc12[12];
#pragma unroll
        for (int rr = 0; rr < 12; ++rr) acc12[rr] = 0.f;
        for (int ccix = 0; ccix < 4; ++ccix) {
            float xv[64];
#pragma unroll
            for (int j = 0; j < 64; ++j) xv[j] = xb[(size_t)(ccix * 64 + j) * HWSZ];
#pragma unroll
            for (int rr = 0; rr < 12; ++rr) {
                int row = wv * 12 + rr;
                int wr = (row < 16) ? (h * 16 + row)
                       : (row < 32) ? (256 + h * 16 + row - 16)
                                    : (512 + h * 16 + row - 32);
                const float* wp = qkvw + (size_t)wr * 256 + ccix * 64;
                float s0 = 0.f, s1 = 0.f, s2 = 0.f, s3 = 0.f;
#pragma unroll
                for (int j = 0; j < 64; j += 4) {
                    s0 += wp[j + 0] * xv[j + 0];
                    s1 += wp[j + 1] * xv[j + 1];
                    s2 += wp[j + 2] * xv[j + 2];
                    s3 += wp[j + 3] * xv[j + 3];
                }
                acc12[rr] += (s0 + s1) + (s2 + s3);
            }
        }
#pragma unroll
        for (int rr = 0; rr < 12; ++rr) qkvb[wv * 12 + rr][lane] = acc12[rr];
        __syncthreads();

        // ---- attention: row irow, j-range jg*16..jg*16+15
        float qd[16];
#pragma unroll
        for (int d = 0; d < 16; ++d) qd[d] = qkvb[d][irow];
        float s[16];
#pragma unroll
        for (int jj = 0; jj < 16; ++jj) s[jj] = 0.f;
#pragma unroll
        for (int d = 0; d < 16; ++d) {
            const float* kp = &qkvb[16 + d][jg * 16];
#pragma unroll
            for (int m = 0; m < 4; ++m) {
                float4 kv = *(const float4*)(kp + m * 4);
                s[m * 4 + 0] += qd[d] * kv.x;
                s[m * 4 + 1] += qd[d] * kv.y;
                s[m * 4 + 2] += qd[d] * kv.z;
                s[m * 4 + 3] += qd[d] * kv.w;
            }
        }
#pragma unroll
        for (int jj = 0; jj < 16; ++jj) {
            int j = jg * 16 + jj;
            int jy = j >> 3, jx = j & 7;
            int rpi = (iy - jy + 7) * 15 + (ix - jx + 7);
            s[jj] = s[jj] * 0.25f + bt[rpi * 16 + h];
        }
        float mx = s[0];
#pragma unroll
        for (int jj = 1; jj < 16; ++jj) mx = fmaxf(mx, s[jj]);
        mx = fmaxf(mx, __shfl_xor(mx, 16));
        mx = fmaxf(mx, __shfl_xor(mx, 32));
        float ls = 0.f;
#pragma unroll
        for (int jj = 0; jj < 16; ++jj) { s[jj] = __expf(s[jj] - mx); ls += s[jj]; }
        ls += __shfl_xor(ls, 16);
        ls += __shfl_xor(ls, 32);
        float inv = 1.0f / ls;
#pragma unroll
        for (int d = 0; d < 16; ++d) {
            const float* vp = &qkvb[32 + d][jg * 16];
            float o0 = 0.f, o1 = 0.f;
#pragma unroll
            for (int m = 0; m < 4; ++m) {
                float4 vvv = *(const float4*)(vp + m * 4);
                o0 += s[m * 4 + 0] * vvv.x + s[m * 4 + 1] * vvv.y;
                o1 += s[m * 4 + 2] * vvv.z + s[m * 4 + 3] * vvv.w;
            }
            float o = o0 + o1;
            o += __shfl_xor(o, 16);
            o += __shfl_xor(o, 32);
            if (jg == 0)
                attnout[((size_t)(b * CCH + h * 16 + d)) * HWSZ + (y0 + iy) * 128 + (x0 + ix)] = o * inv;
        }
    }
}

// ---------------- dual avg-pool + add local
__global__ __launch_bounds__(256) void k_pools(const float* __restrict__ attnout, const float* __restrict__ localb,
                                               float* __restrict__ sbuf) {
    for (int i = blockIdx.x * 256 + threadIdx.x; i < 4 * CCH * HWSZ; i += gridDim.x * 256) {
        int xc = i & 127;
        int y  = (i >> 7) & 127;
        int bc = i >> 14;
        const float* pl = attnout + (size_t)bc * HWSZ;
        float axs = 0.f;
#pragma unroll
        for (int d = -3; d <= 4; ++d) {
            int t2 = y + d;
            if (t2 >= 0 && t2 < 128) axs += pl[t2 * 128 + xc];
        }
        if (y >= 124) axs += pl[126 * 128 + xc];
        float ays = 0.f;
#pragma unroll
        for (int d = -3; d <= 4; ++d) {
            int t2 = xc + d;
            if (t2 >= 0 && t2 < 128) ays += pl[y * 128 + t2];
        }
        if (xc >= 124) ays += pl[y * 128 + 126];
        sbuf[i] = (axs + ays) * 0.125f + localb[i];
    }
}

// ---------------- depthwise 8x8 (reflect +1 pad, zero pad 3) + bn
__device__ __forceinline__ void dw_loadrow(const float* __restrict__ sp, int trow, int j, float* dst) {
    if (trow < 0 || trow > 128) {
#pragma unroll
        for (int q = 0; q < 8; ++q) dst[q] = 0.f;
        return;
    }
    int sr = (trow == 128) ? 126 : trow;
    const float* rp = sp + sr * 128;
#pragma unroll
    for (int q = 0; q < 8; ++q) {
        int col = j - 3 + q;
        float v = 0.f;
        if (col >= 0 && col <= 128) v = rp[(col == 128) ? 126 : col];
        dst[q] = v;
    }
}

__global__ __launch_bounds__(256) void k_dw(const float* __restrict__ sbuf, const float* __restrict__ dww,
                                            const float* __restrict__ pscale, const float* __restrict__ pbias,
                                            float* __restrict__ tbuf) {
    int t = threadIdx.x;
    int j = t & 127;
    int half = __builtin_amdgcn_readfirstlane(t >> 7);
    int bid = blockIdx.x;          // 0..511
    int c = (bid & 127) * 2 + half;
    int b = bid >> 7;
    const float* sp = sbuf + ((size_t)(b * CCH + c)) * HWSZ;
    float wloc[64];
    const float* dwp = dww + c * 64;
#pragma unroll
    for (int i = 0; i < 64; ++i) wloc[i] = dwp[i];
    float scale = pscale[c], bias = pbias[c];

    float rbuf[8][8];
#pragma unroll
    for (int tr = -3; tr <= 4; ++tr) {
        dw_loadrow(sp, tr, j, rbuf[(tr + 8) & 7]);
    }
    float* op = tbuf + ((size_t)(b * CCH + c)) * HWSZ;
    for (int yb = 0; yb < 16; ++yb) {
#pragma unroll
        for (int k = 0; k < 8; ++k) {
            int y = yb * 8 + k;
            float a0 = 0.f, a1 = 0.f, a2 = 0.f, a3 = 0.f;
#pragma unroll
            for (int p = 0; p < 8; ++p) {
                const int slot = (k + 5 + p) & 7;
                float part = 0.f;
#pragma unroll
                for (int q = 0; q < 8; ++q) part += wloc[p * 8 + q] * rbuf[slot][q];
                if ((p & 3) == 0) a0 += part;
                else if ((p & 3) == 1) a1 += part;
                else if ((p & 3) == 2) a2 += part;
                else a3 += part;
            }
            op[y * 128 + j] = scale * ((a0 + a1) + (a2 + a3)) + bias;
            dw_loadrow(sp, y + 5, j, rbuf[(k + 5) & 7]);
        }
    }
}

// ---------------- pointwise 1x1 conv: 64co x 128px (one row) per WG
__global__ __launch_bounds__(256) void k_pw(const float* __restrict__ tbuf, const float* __restrict__ pww,
                                            float* __restrict__ outp) {
    __shared__ __align__(16) float xs[8][128];
    __shared__ __align__(16) float wsm[8][64];
    int t = threadIdx.x;
    int bid = blockIdx.x;
    int cb = bid & 3;
    int row = bid >> 2;          // 0..511
    int y = row & 127;
    int b = row >> 7;
    int cg = t >> 4;             // 0..15
    int px = (t & 15) * 8;
    float acc[4][8];
#pragma unroll
    for (int c = 0; c < 4; ++c)
#pragma unroll
        for (int j = 0; j < 8; ++j) acc[c][j] = 0.f;
    const float* tb = tbuf + (size_t)b * CCH * HWSZ + y * 128;

    for (int cc = 0; cc < 32; ++cc) {
        __syncthreads();
        {
            int i = t;
#pragma unroll
            for (int it = 0; it < 4; ++it, i += 256) {
                int ci = i >> 7, p = i & 127;
                xs[ci][p] = tb[(size_t)(cc * 8 + ci) * HWSZ + p];
            }
        }
        for (int i = t; i < 512; i += 256) {
            int ci = i >> 6, co = i & 63;
            wsm[ci][co] = pww[(size_t)(cb * 64 + co) * 256 + cc * 8 + ci];
        }
        __syncthreads();
#pragma unroll
        for (int ci = 0; ci < 8; ++ci) {
            float4 w = *(const float4*)&wsm[ci][cg * 4];
            float4 xa = *(const float4*)&xs[ci][px];
            float4 xbv = *(const float4*)&xs[ci][px + 4];
            float xf[8] = {xa.x, xa.y, xa.z, xa.w, xbv.x, xbv.y, xbv.z, xbv.w};
#pragma unroll
            for (int j = 0; j < 8; ++j) {
                acc[0][j] += w.x * xf[j];
                acc[1][j] += w.y * xf[j];
                acc[2][j] += w.z * xf[j];
                acc[3][j] += w.w * xf[j];
            }
        }
    }
#pragma unroll
    for (int c = 0; c < 4; ++c) {
        int co = cb * 64 + cg * 4 + c;
        float* op = outp + ((size_t)(b * CCH + co)) * HWSZ + y * 128 + px;
        *(float4*)op = make_float4(acc[c][0], acc[c][1], acc[c][2], acc[c][3]);
        *(float4*)(op + 4) = make_float4(acc[c][4], acc[c][5], acc[c][6], acc[c][7]);
    }
}

extern "C" void kernel_launch(void* const* d_in, const int* in_sizes, int n_in,
                              void* d_out, int out_size, void* d_ws, size_t ws_size,
                              hipStream_t stream) {
    const float* x    = (const float*)d_in[0];
    const float* qkvw = (const float*)d_in[1];
    const float* l1w  = (const float*)d_in[2];
    const float* l1s  = (const float*)d_in[3];
    const float* l1b  = (const float*)d_in[4];
    const float* l2w  = (const float*)d_in[5];
    const float* l2s  = (const float*)d_in[6];
    const float* l2b  = (const float*)d_in[7];
    const float* dww  = (const float*)d_in[8];
    const float* ps   = (const float*)d_in[9];
    const float* pb   = (const float*)d_in[10];
    const float* pww  = (const float*)d_in[11];
    const float* bt   = (const float*)d_in[12];
    float* out = (float*)d_out;
    float* wsf = (float*)d_ws;

    const size_t nWf = 589824;          // 2304*256
    const size_t nPlane = 16777216;     // 4*256*128*128
    size_t need = (nWf + 256 + 3 * nPlane) * sizeof(float);
    if (ws_size < need) return;         // insufficient workspace: bail (signals wrong-answer, not corruption)

    float* Wf      = wsf;
    float* biasf   = wsf + nWf;
    float* attnout = wsf + nWf + 256;
    float* localb  = attnout + nPlane;
    float* sbuf    = localb + nPlane;
    float* tbuf    = attnout;           // attnout dead after k_pools

    k_fold <<<2304, 256, 0, stream>>>(l1w, l1s, l1b, l2w, l2s, l2b, Wf, biasf);
    k_conv3<<<2048, 256, 0, stream>>>(x, Wf, biasf, localb);
    k_attn <<<1024, 256, 0, stream>>>(x, qkvw, bt, attnout);
    k_pools<<<4096, 256, 0, stream>>>(attnout, localb, sbuf);
    k_dw   <<<512,  256, 0, stream>>>(sbuf, dww, ps, pb, tbuf);
    k_pw   <<<2048, 256, 0, stream>>>(tbuf, pww, out);
}

// Round 2
// 2893.681 us; speedup vs baseline: 1.1000x; 1.1000x over previous
//
#include <hip/hip_runtime.h>
#include <cstddef>

#define HH 128
#define WW2 128
#define HWSZ (HH*WW2)
#define CCH 256

// ---------------- fold: Wf[ci][k][co] = l1s*l1w (+ center: l2s*l2w); biasf = l1b+l2b
__global__ __launch_bounds__(256) void k_fold(const float* __restrict__ l1w, const float* __restrict__ l1s,
                                              const float* __restrict__ l1b, const float* __restrict__ l2w,
                                              const float* __restrict__ l2s, const float* __restrict__ l2b,
                                              float* __restrict__ Wf, float* __restrict__ biasf) {
    int idx = blockIdx.x * 256 + threadIdx.x;
    if (idx < 2304 * 256) {
        int co = idx & 255;
        int i2 = idx >> 8;           // 0..2303 = ci*9+k
        int ci = i2 / 9;
        int k  = i2 - ci * 9;
        float w = l1s[co] * l1w[co * 2304 + ci * 9 + k];
        if (k == 4) w += l2s[co] * l2w[co * 256 + ci];
        Wf[i2 * 256 + co] = w;
    }
    if (idx < 256) biasf[idx] = l1b[idx] + l2b[idx];
}

// ---------------- fused 3x3 conv (local path): 64co x (16 rows x 8 cols) tile
__global__ __launch_bounds__(256) void k_conv3(const float* __restrict__ x, const float* __restrict__ Wf,
                                               const float* __restrict__ biasf, float* __restrict__ outp) {
    __shared__ __align__(16) float xs[8][18][12];
    __shared__ __align__(16) float wsm[8][9][64];
    int t = threadIdx.x;
    int bid = blockIdx.x;
    int cb = bid & 3;
    int tile = bid >> 2;
    int tx = tile & 15;
    int ty = (tile >> 4) & 7;
    int b = tile >> 7;
    int x0 = tx * 8, y0 = ty * 16;
    int cg = t >> 4;   // 0..15 (4 co each)
    int r  = t & 15;   // row within tile

    float acc[4][8];
#pragma unroll
    for (int c = 0; c < 4; ++c)
#pragma unroll
        for (int j = 0; j < 8; ++j) acc[c][j] = 0.f;

    const float* xb = x + (size_t)b * CCH * HWSZ;

    for (int cc = 0; cc < 32; ++cc) {
        __syncthreads();
        for (int i = t; i < 1728; i += 256) {  // 8ci x 18r x 12c
            int ci = i / 216; int rem = i - ci * 216;
            int rr = rem / 12; int c = rem - rr * 12;
            int gy = y0 - 1 + rr; int gx = x0 - 1 + c;
            float v = 0.f;
            if (c < 10 && gy >= 0 && gy < 128 && gx >= 0 && gx < 128)
                v = xb[(size_t)(cc * 8 + ci) * HWSZ + gy * 128 + gx];
            xs[ci][rr][c] = v;
        }
        for (int i = t; i < 4608; i += 256) {  // 8ci x 9k x 64co
            int ci = i / 576; int rem = i - ci * 576;
            int k = rem >> 6; int co = rem & 63;
            wsm[ci][k][co] = Wf[(size_t)((cc * 8 + ci) * 9 + k) * 256 + cb * 64 + co];
        }
        __syncthreads();
#pragma unroll
        for (int ci = 0; ci < 8; ++ci) {
            float xf[3][12];
#pragma unroll
            for (int dy = 0; dy < 3; ++dy) {
#pragma unroll
                for (int m = 0; m < 3; ++m) {
                    float4 tmp = *(const float4*)&xs[ci][r + dy][m * 4];
                    xf[dy][m * 4 + 0] = tmp.x; xf[dy][m * 4 + 1] = tmp.y;
                    xf[dy][m * 4 + 2] = tmp.z; xf[dy][m * 4 + 3] = tmp.w;
                }
            }
#pragma unroll
            for (int dy = 0; dy < 3; ++dy) {
#pragma unroll
                for (int dx = 0; dx < 3; ++dx) {
                    float4 w = *(const float4*)&wsm[ci][dy * 3 + dx][cg * 4];
#pragma unroll
                    for (int j = 0; j < 8; ++j) {
                        float xv = xf[dy][j + dx];
                        acc[0][j] += w.x * xv;
                        acc[1][j] += w.y * xv;
                        acc[2][j] += w.z * xv;
                        acc[3][j] += w.w * xv;
                    }
                }
            }
        }
    }
    int y = y0 + r;
#pragma unroll
    for (int c = 0; c < 4; ++c) {
        int co = cb * 64 + cg * 4 + c;
        float bv = biasf[co];
        float* op = outp + ((size_t)(b * CCH + co)) * HWSZ + y * 128 + x0;
        float4 o0 = make_float4(acc[c][0] + bv, acc[c][1] + bv, acc[c][2] + bv, acc[c][3] + bv);
        float4 o1 = make_float4(acc[c][4] + bv, acc[c][5] + bv, acc[c][6] + bv, acc[c][7] + bv);
        *(float4*)op = o0;
        *(float4*)(op + 4) = o1;
    }
}

// ---------------- fused qkv + window attention: one WG per 8x8 window
// LDS: xs = 256ch x 64tok fp32 (64 KB, staged ONCE), qkvb = 48 x 64 (12 KB per head)
__global__ __launch_bounds__(256) void k_attn(const float* __restrict__ x, const float* __restrict__ qkvw,
                                              const float* __restrict__ bt, float* __restrict__ attnout) {
    extern __shared__ float smem[];
    float* xs   = smem;            // [256][64]
    float* qkvb = smem + 16384;    // [48][64]

    int t = threadIdx.x;
    int wv = __builtin_amdgcn_readfirstlane(t >> 6);
    int lane = t & 63;
    int widx = blockIdx.x;
    int b = widx >> 8;
    int rem = widx & 255;
    int hy = rem >> 4, wx = rem & 15;
    int y0 = hy * 8, x0 = wx * 8;
    const float* xb0 = x + (size_t)b * CCH * HWSZ + y0 * 128 + x0;

    // ---- stage x window once: 256 ch x 64 tok, float4 loads
    for (int i = t; i < 4096; i += 256) {
        int ci = i >> 4;
        int q  = i & 15;                       // 16 float4 per channel
        int row = q >> 1, col = (q & 1) * 4;
        float4 v = *(const float4*)(xb0 + (size_t)ci * HWSZ + row * 128 + col);
        *(float4*)&xs[ci * 64 + q * 4] = v;
    }
    __syncthreads();

    int irow = wv * 16 + (lane & 15);   // attention row this lane helps with
    int jg = lane >> 4;                 // j-quarter 0..3
    int iy = irow >> 3, ix = irow & 7;

    for (int h = 0; h < 16; ++h) {
        // ---- qkv for this head: wave wv computes rows 12*wv .. 12*wv+11, lane = token
        // weight row pointers (wave-uniform -> SGPR, s_load path)
        const float* wrp[12];
#pragma unroll
        for (int rr = 0; rr < 12; ++rr) {
            int r = wv * 12 + rr;
            int wr = (r >> 4) * 256 + h * 16 + (r & 15);
            wrp[rr] = qkvw + (size_t)wr * 256;
        }
        float acc12[12];
#pragma unroll
        for (int rr = 0; rr < 12; ++rr) acc12[rr] = 0.f;

        for (int ci = 0; ci < 256; ci += 4) {
            float xv0 = xs[(ci + 0) * 64 + lane];
            float xv1 = xs[(ci + 1) * 64 + lane];
            float xv2 = xs[(ci + 2) * 64 + lane];
            float xv3 = xs[(ci + 3) * 64 + lane];
#pragma unroll
            for (int rr = 0; rr < 12; ++rr) {
                float4 w = *(const float4*)(wrp[rr] + ci);
                acc12[rr] += w.x * xv0 + w.y * xv1 + w.z * xv2 + w.w * xv3;
            }
        }
        __syncthreads();   // prior-head attention reads of qkvb done
#pragma unroll
        for (int rr = 0; rr < 12; ++rr) qkvb[(wv * 12 + rr) * 64 + lane] = acc12[rr];
        __syncthreads();

        // ---- attention: row irow, j-range jg*16..jg*16+15
        float qd[16];
#pragma unroll
        for (int d = 0; d < 16; ++d) qd[d] = qkvb[d * 64 + irow];
        float s[16];
#pragma unroll
        for (int jj = 0; jj < 16; ++jj) s[jj] = 0.f;
#pragma unroll
        for (int d = 0; d < 16; ++d) {
            const float* kp = &qkvb[(16 + d) * 64 + jg * 16];
#pragma unroll
            for (int m = 0; m < 4; ++m) {
                float4 kv = *(const float4*)(kp + m * 4);
                s[m * 4 + 0] += qd[d] * kv.x;
                s[m * 4 + 1] += qd[d] * kv.y;
                s[m * 4 + 2] += qd[d] * kv.z;
                s[m * 4 + 3] += qd[d] * kv.w;
            }
        }
#pragma unroll
        for (int jj = 0; jj < 16; ++jj) {
            int j = jg * 16 + jj;
            int jy = j >> 3, jx = j & 7;
            int rpi = (iy - jy + 7) * 15 + (ix - jx + 7);
            s[jj] = s[jj] * 0.25f + bt[rpi * 16 + h];
        }
        float mx = s[0];
#pragma unroll
        for (int jj = 1; jj < 16; ++jj) mx = fmaxf(mx, s[jj]);
        mx = fmaxf(mx, __shfl_xor(mx, 16));
        mx = fmaxf(mx, __shfl_xor(mx, 32));
        float ls = 0.f;
#pragma unroll
        for (int jj = 0; jj < 16; ++jj) { s[jj] = __expf(s[jj] - mx); ls += s[jj]; }
        ls += __shfl_xor(ls, 16);
        ls += __shfl_xor(ls, 32);
        float inv = 1.0f / ls;
#pragma unroll
        for (int d = 0; d < 16; ++d) {
            const float* vp = &qkvb[(32 + d) * 64 + jg * 16];
            float o0 = 0.f, o1 = 0.f;
#pragma unroll
            for (int m = 0; m < 4; ++m) {
                float4 vvv = *(const float4*)(vp + m * 4);
                o0 += s[m * 4 + 0] * vvv.x + s[m * 4 + 1] * vvv.y;
                o1 += s[m * 4 + 2] * vvv.z + s[m * 4 + 3] * vvv.w;
            }
            float o = o0 + o1;
            o += __shfl_xor(o, 16);
            o += __shfl_xor(o, 32);
            if (jg == 0)
                attnout[((size_t)(b * CCH + h * 16 + d)) * HWSZ + (y0 + iy) * 128 + (x0 + ix)] = o * inv;
        }
    }
}

// ---------------- dual avg-pool + add local
__global__ __launch_bounds__(256) void k_pools(const float* __restrict__ attnout, const float* __restrict__ localb,
                                               float* __restrict__ sbuf) {
    for (int i = blockIdx.x * 256 + threadIdx.x; i < 4 * CCH * HWSZ; i += gridDim.x * 256) {
        int xc = i & 127;
        int y  = (i >> 7) & 127;
        int bc = i >> 14;
        const float* pl = attnout + (size_t)bc * HWSZ;
        float axs = 0.f;
#pragma unroll
        for (int d = -3; d <= 4; ++d) {
            int t2 = y + d;
            if (t2 >= 0 && t2 < 128) axs += pl[t2 * 128 + xc];
        }
        if (y >= 124) axs += pl[126 * 128 + xc];
        float ays = 0.f;
#pragma unroll
        for (int d = -3; d <= 4; ++d) {
            int t2 = xc + d;
            if (t2 >= 0 && t2 < 128) ays += pl[y * 128 + t2];
        }
        if (xc >= 124) ays += pl[y * 128 + 126];
        sbuf[i] = (axs + ays) * 0.125f + localb[i];
    }
}

// ---------------- depthwise 8x8 (reflect +1 pad, zero pad 3) + bn
__device__ __forceinline__ void dw_loadrow(const float* __restrict__ sp, int trow, int j, float* dst) {
    if (trow < 0 || trow > 128) {
#pragma unroll
        for (int q = 0; q < 8; ++q) dst[q] = 0.f;
        return;
    }
    int sr = (trow == 128) ? 126 : trow;
    const float* rp = sp + sr * 128;
#pragma unroll
    for (int q = 0; q < 8; ++q) {
        int col = j - 3 + q;
        float v = 0.f;
        if (col >= 0 && col <= 128) v = rp[(col == 128) ? 126 : col];
        dst[q] = v;
    }
}

__global__ __launch_bounds__(256) void k_dw(const float* __restrict__ sbuf, const float* __restrict__ dww,
                                            const float* __restrict__ pscale, const float* __restrict__ pbias,
                                            float* __restrict__ tbuf) {
    int t = threadIdx.x;
    int j = t & 127;
    int half = __builtin_amdgcn_readfirstlane(t >> 7);
    int bid = blockIdx.x;          // 0..511
    int c = (bid & 127) * 2 + half;
    int b = bid >> 7;
    const float* sp = sbuf + ((size_t)(b * CCH + c)) * HWSZ;
    float wloc[64];
    const float* dwp = dww + c * 64;
#pragma unroll
    for (int i = 0; i < 64; ++i) wloc[i] = dwp[i];
    float scale = pscale[c], bias = pbias[c];

    float rbuf[8][8];
#pragma unroll
    for (int tr = -3; tr <= 4; ++tr) {
        dw_loadrow(sp, tr, j, rbuf[(tr + 8) & 7]);
    }
    float* op = tbuf + ((size_t)(b * CCH + c)) * HWSZ;
    for (int yb = 0; yb < 16; ++yb) {
#pragma unroll
        for (int k = 0; k < 8; ++k) {
            int y = yb * 8 + k;
            float a0 = 0.f, a1 = 0.f, a2 = 0.f, a3 = 0.f;
#pragma unroll
            for (int p = 0; p < 8; ++p) {
                const int slot = (k + 5 + p) & 7;
                float part = 0.f;
#pragma unroll
                for (int q = 0; q < 8; ++q) part += wloc[p * 8 + q] * rbuf[slot][q];
                if ((p & 3) == 0) a0 += part;
                else if ((p & 3) == 1) a1 += part;
                else if ((p & 3) == 2) a2 += part;
                else a3 += part;
            }
            op[y * 128 + j] = scale * ((a0 + a1) + (a2 + a3)) + bias;
            dw_loadrow(sp, y + 5, j, rbuf[(k + 5) & 7]);
        }
    }
}

// ---------------- pointwise 1x1 conv: 64co x 128px (one row) per WG
__global__ __launch_bounds__(256) void k_pw(const float* __restrict__ tbuf, const float* __restrict__ pww,
                                            float* __restrict__ outp) {
    __shared__ __align__(16) float xs[8][128];
    __shared__ __align__(16) float wsm[8][64];
    int t = threadIdx.x;
    int bid = blockIdx.x;
    int cb = bid & 3;
    int row = bid >> 2;          // 0..511
    int y = row & 127;
    int b = row >> 7;
    int cg = t >> 4;             // 0..15
    int px = (t & 15) * 8;
    float acc[4][8];
#pragma unroll
    for (int c = 0; c < 4; ++c)
#pragma unroll
        for (int j = 0; j < 8; ++j) acc[c][j] = 0.f;
    const float* tb = tbuf + (size_t)b * CCH * HWSZ + y * 128;

    for (int cc = 0; cc < 32; ++cc) {
        __syncthreads();
        {
            int i = t;
#pragma unroll
            for (int it = 0; it < 4; ++it, i += 256) {
                int ci = i >> 7, p = i & 127;
                xs[ci][p] = tb[(size_t)(cc * 8 + ci) * HWSZ + p];
            }
        }
        for (int i = t; i < 512; i += 256) {
            int ci = i >> 6, co = i & 63;
            wsm[ci][co] = pww[(size_t)(cb * 64 + co) * 256 + cc * 8 + ci];
        }
        __syncthreads();
#pragma unroll
        for (int ci = 0; ci < 8; ++ci) {
            float4 w = *(const float4*)&wsm[ci][cg * 4];
            float4 xa = *(const float4*)&xs[ci][px];
            float4 xbv = *(const float4*)&xs[ci][px + 4];
            float xf[8] = {xa.x, xa.y, xa.z, xa.w, xbv.x, xbv.y, xbv.z, xbv.w};
#pragma unroll
            for (int j = 0; j < 8; ++j) {
                acc[0][j] += w.x * xf[j];
                acc[1][j] += w.y * xf[j];
                acc[2][j] += w.z * xf[j];
                acc[3][j] += w.w * xf[j];
            }
        }
    }
#pragma unroll
    for (int c = 0; c < 4; ++c) {
        int co = cb * 64 + cg * 4 + c;
        float* op = outp + ((size_t)(b * CCH + co)) * HWSZ + y * 128 + px;
        *(float4*)op = make_float4(acc[c][0], acc[c][1], acc[c][2], acc[c][3]);
        *(float4*)(op + 4) = make_float4(acc[c][4], acc[c][5], acc[c][6], acc[c][7]);
    }
}

extern "C" void kernel_launch(void* const* d_in, const int* in_sizes, int n_in,
                              void* d_out, int out_size, void* d_ws, size_t ws_size,
                              hipStream_t stream) {
    const float* x    = (const float*)d_in[0];
    const float* qkvw = (const float*)d_in[1];
    const float* l1w  = (const float*)d_in[2];
    const float* l1s  = (const float*)d_in[3];
    const float* l1b  = (const float*)d_in[4];
    const float* l2w  = (const float*)d_in[5];
    const float* l2s  = (const float*)d_in[6];
    const float* l2b  = (const float*)d_in[7];
    const float* dww  = (const float*)d_in[8];
    const float* ps   = (const float*)d_in[9];
    const float* pb   = (const float*)d_in[10];
    const float* pww  = (const float*)d_in[11];
    const float* bt   = (const float*)d_in[12];
    float* out = (float*)d_out;
    float* wsf = (float*)d_ws;

    const size_t nWf = 589824;          // 2304*256
    const size_t nPlane = 16777216;     // 4*256*128*128
    size_t need = (nWf + 256 + 3 * nPlane) * sizeof(float);
    if (ws_size < need) return;         // insufficient workspace: bail

    float* Wf      = wsf;
    float* biasf   = wsf + nWf;
    float* attnout = wsf + nWf + 256;
    float* localb  = attnout + nPlane;
    float* sbuf    = localb + nPlane;
    float* tbuf    = attnout;           // attnout dead after k_pools

    // 76 KB dynamic LDS for k_attn (xs 64KB + qkvb 12KB)
    const int attn_lds = (16384 + 3072) * sizeof(float);
    hipFuncSetAttribute((const void*)k_attn, hipFuncAttributeMaxDynamicSharedMemorySize, attn_lds);

    k_fold <<<2304, 256, 0, stream>>>(l1w, l1s, l1b, l2w, l2s, l2b, Wf, biasf);
    k_conv3<<<2048, 256, 0, stream>>>(x, Wf, biasf, localb);
    k_attn <<<1024, 256, attn_lds, stream>>>(x, qkvw, bt, attnout);
    k_pools<<<4096, 256, 0, stream>>>(attnout, localb, sbuf);
    k_dw   <<<512,  256, 0, stream>>>(sbuf, dww, ps, pb, tbuf);
    k_pw   <<<2048, 256, 0, stream>>>(tbuf, pww, out);
}

// Round 3
// 1877.539 us; speedup vs baseline: 1.6953x; 1.5412x over previous
//
#include <hip/hip_runtime.h>
#include <cstddef>

#define HH 128
#define WW2 128
#define HWSZ (HH*WW2)
#define CCH 256

typedef __attribute__((ext_vector_type(8))) short short8v;   // 8 bf16 = 4 VGPR
typedef __attribute__((ext_vector_type(16))) float f32x16;   // MFMA 32x32 acc

__device__ __forceinline__ ushort bf16rte(float v) {
    uint u = __float_as_uint(v);
    uint r = u + 0x7FFFu + ((u >> 16) & 1u);
    return (ushort)(r >> 16);
}

// ---------------- fold: Wf[ci*9+k][co] = l1s*l1w (+ center: l2s*l2w); biasf = l1b+l2b
__global__ __launch_bounds__(256) void k_fold(const float* __restrict__ l1w, const float* __restrict__ l1s,
                                              const float* __restrict__ l1b, const float* __restrict__ l2w,
                                              const float* __restrict__ l2s, const float* __restrict__ l2b,
                                              float* __restrict__ Wf, float* __restrict__ biasf) {
    int idx = blockIdx.x * 256 + threadIdx.x;
    if (idx < 2304 * 256) {
        int co = idx & 255;
        int i2 = idx >> 8;           // 0..2303 = ci*9+k
        int ci = i2 / 9;
        int k  = i2 - ci * 9;
        float w = l1s[co] * l1w[co * 2304 + ci * 9 + k];
        if (k == 4) w += l2s[co] * l2w[co * 256 + ci];
        Wf[i2 * 256 + co] = w;
    }
    if (idx < 256) biasf[idx] = l1b[idx] + l2b[idx];
}

// ---------------- weight split into A-fragment order, hi/lo bf16 planes
// Afrag[co_blk(8)][kb(144)][lane(64)][8]; kb = cc*18 + tap*2 + ks
// element: co = co_blk*32 + (lane&31); ci = cc*32 + ks*16 + (lane>>5)*8 + j
__global__ __launch_bounds__(256) void k_wsplit(const float* __restrict__ Wf,
                                                ushort* __restrict__ ahi, ushort* __restrict__ alo) {
    int idx = blockIdx.x * 256 + threadIdx.x;     // 589824 total
    if (idx >= 589824) return;
    int j    = idx & 7;
    int lane = (idx >> 3) & 63;
    int t2   = idx >> 9;
    int kb   = t2 % 144;
    int cob  = t2 / 144;
    int cc  = kb / 18; int rem = kb - cc * 18; int tap = rem >> 1; int ks = rem & 1;
    int ci  = cc * 32 + ks * 16 + ((lane >> 5) << 3) + j;
    int co  = cob * 32 + (lane & 31);
    float v = Wf[(size_t)(ci * 9 + tap) * 256 + co];
    ushort h = bf16rte(v);
    float hf = __uint_as_float((uint)h << 16);
    ushort l = bf16rte(v - hf);
    ahi[idx] = h;
    alo[idx] = l;
}

// ---------------- x -> pixel-major bf16 hi/lo planes: xT[b][pix][256ci]
__global__ __launch_bounds__(256) void k_cvt(const float* __restrict__ x,
                                             ushort* __restrict__ xhi, ushort* __restrict__ xlo) {
    __shared__ uint pk[32 * 265];
    int t = threadIdx.x;
    int bid = blockIdx.x;               // 4 * 512
    int b = bid >> 9;
    int px0 = (bid & 511) * 32;
    const float* xb = x + (size_t)b * CCH * HWSZ;
    for (int step = 0; step < 32; ++step) {
        int ci = step * 8 + (t >> 5);
        float v = xb[(size_t)ci * HWSZ + px0 + (t & 31)];
        ushort h = bf16rte(v);
        float hf = __uint_as_float((uint)h << 16);
        ushort l = bf16rte(v - hf);
        pk[(t & 31) * 265 + ci] = ((uint)h << 16) | l;
    }
    __syncthreads();
    int pxl = t >> 3, o = t & 7;
    uint* hp = (uint*)xhi;
    uint* lp = (uint*)xlo;
    size_t pb2 = ((size_t)b * HWSZ + px0 + pxl) * 128;
#pragma unroll
    for (int m = 0; m < 16; ++m) {
        int cip = m * 16 + o * 2;
        uint p0 = pk[pxl * 265 + cip];
        uint p1 = pk[pxl * 265 + cip + 1];
        hp[pb2 + m * 8 + o] = (p1 & 0xFFFF0000u) | (p0 >> 16);
        lp[pb2 + m * 8 + o] = (p1 << 16) | (p0 & 0xFFFFu);
    }
}

// ---------------- conv3x3 as implicit GEMM via mfma_f32_32x32x16_bf16 (3-term split)
// block: 128co x 128px(8r x 16c); 4 waves: wave = 64co x 64px(4r x 16c)
// LDS: X patch [2 planes][180 locs(10r x 18c)][36 ci-pad] bf16 = 25920 B
__global__ __launch_bounds__(256) void k_conv3m(const ushort* __restrict__ xhi, const ushort* __restrict__ xlo,
                                                const ushort* __restrict__ afr_hi, const ushort* __restrict__ afr_lo,
                                                const float* __restrict__ biasf, float* __restrict__ outp) {
    __shared__ __align__(16) ushort Xsh[12960];   // hi at byte 0, lo at byte 12960
    char* xsb = (char*)Xsh;

    int t = threadIdx.x;
    int bid = blockIdx.x;
    int cb = bid & 1;
    int t2 = bid >> 1;
    int tile_c = t2 & 7;
    int tile_r = (t2 >> 3) & 15;
    int b = t2 >> 7;
    int x0 = tile_c * 16, y0 = tile_r * 8;

    int w = t >> 6, lane = t & 63;
    int co_w = cb * 128 + (w >> 1) * 64;       // a-frags at co_w, co_w+32
    int pr0 = (w & 1) * 4;                     // wave's 4 tile rows
    int pr_l = (lane & 31) >> 4;               // row within 2-row frag
    int pc = lane & 15;                        // col
    int kl = lane >> 5;                        // k-half
    // per-frag LDS lane base (bytes): row stride 72B, f adds 2 rows
    int lb0 = (pr0 + 0 + pr_l) * 1296 + pc * 72 + kl * 16;
    int lb1 = (pr0 + 2 + pr_l) * 1296 + pc * 72 + kl * 16;

    const short8v* Ahi = (const short8v*)afr_hi;
    const short8v* Alo = (const short8v*)afr_lo;
    int cobase = (co_w >> 5) * 144 * 64;       // co_blk * 144 * 64

    f32x16 c00 = {}, c01 = {}, c10 = {}, c11 = {};

    for (int cc = 0; cc < 8; ++cc) {
        __syncthreads();
#pragma unroll
        for (int it = 0; it < 6; ++it) {
            int i = t + it * 256;
            if (i < 1440) {
                int oct = i & 3;
                int j2 = i >> 2;
                int plane = j2 & 1;
                int loc = j2 >> 1;             // 0..179
                int r = loc / 18, c = loc - r * 18;
                int gy = y0 - 1 + r, gx = x0 - 1 + c;
                uint4 v = make_uint4(0u, 0u, 0u, 0u);
                if (gy >= 0 && gy < 128 && gx >= 0 && gx < 128) {
                    const ushort* src = plane ? xlo : xhi;
                    v = *(const uint4*)(src + ((size_t)(b * HWSZ + gy * 128 + gx) * 256 + cc * 32 + oct * 8));
                }
                *(uint4*)(xsb + plane * 12960 + loc * 72 + oct * 16) = v;
            }
        }
        __syncthreads();

        int baseA = cobase + cc * 18 * 64 + lane;
#pragma unroll
        for (int tap = 0; tap < 9; ++tap) {
            const int ky = tap / 3, kx = tap - ky * 3;
#pragma unroll
            for (int ks = 0; ks < 2; ++ks) {
                const int boff = ky * 1296 + kx * 72 + ks * 32;
                short8v b0h = *(const short8v*)(xsb + lb0 + boff);
                short8v b0l = *(const short8v*)(xsb + lb0 + boff + 12960);
                short8v b1h = *(const short8v*)(xsb + lb1 + boff);
                short8v b1l = *(const short8v*)(xsb + lb1 + boff + 12960);
                int ai = baseA + (tap * 2 + ks) * 64;
                short8v a0h = Ahi[ai];
                short8v a0l = Alo[ai];
                short8v a1h = Ahi[ai + 144 * 64];
                short8v a1l = Alo[ai + 144 * 64];
                c00 = __builtin_amdgcn_mfma_f32_32x32x16_bf16(a0h, b0h, c00, 0, 0, 0);
                c00 = __builtin_amdgcn_mfma_f32_32x32x16_bf16(a0h, b0l, c00, 0, 0, 0);
                c00 = __builtin_amdgcn_mfma_f32_32x32x16_bf16(a0l, b0h, c00, 0, 0, 0);
                c01 = __builtin_amdgcn_mfma_f32_32x32x16_bf16(a0h, b1h, c01, 0, 0, 0);
                c01 = __builtin_amdgcn_mfma_f32_32x32x16_bf16(a0h, b1l, c01, 0, 0, 0);
                c01 = __builtin_amdgcn_mfma_f32_32x32x16_bf16(a0l, b1h, c01, 0, 0, 0);
                c10 = __builtin_amdgcn_mfma_f32_32x32x16_bf16(a1h, b0h, c10, 0, 0, 0);
                c10 = __builtin_amdgcn_mfma_f32_32x32x16_bf16(a1h, b0l, c10, 0, 0, 0);
                c10 = __builtin_amdgcn_mfma_f32_32x32x16_bf16(a1l, b0h, c10, 0, 0, 0);
                c11 = __builtin_amdgcn_mfma_f32_32x32x16_bf16(a1h, b1h, c11, 0, 0, 0);
                c11 = __builtin_amdgcn_mfma_f32_32x32x16_bf16(a1h, b1l, c11, 0, 0, 0);
                c11 = __builtin_amdgcn_mfma_f32_32x32x16_bf16(a1l, b1h, c11, 0, 0, 0);
            }
        }
    }

    // epilogue: D col = lane&31 (px), row = (r&3)+8*(r>>2)+4*kl (co within 32)
    int colg = x0 + pc;
    int row0 = y0 + pr0 + pr_l;        // f = 0
    int row1 = row0 + 2;               // f = 1
#pragma unroll
    for (int r = 0; r < 16; ++r) {
        int rr = (r & 3) + 8 * (r >> 2) + 4 * kl;
        {
            int co = co_w + rr;
            float bv = biasf[co];
            float* ob = outp + ((size_t)(b * CCH + co)) * HWSZ;
            ob[row0 * 128 + colg] = c00[r] + bv;
            ob[row1 * 128 + colg] = c01[r] + bv;
        }
        {
            int co = co_w + 32 + rr;
            float bv = biasf[co];
            float* ob = outp + ((size_t)(b * CCH + co)) * HWSZ;
            ob[row0 * 128 + colg] = c10[r] + bv;
            ob[row1 * 128 + colg] = c11[r] + bv;
        }
    }
}

// ---------------- fused qkv + window attention: one WG per 8x8 window
__global__ __launch_bounds__(256) void k_attn(const float* __restrict__ x, const float* __restrict__ qkvw,
                                              const float* __restrict__ bt, float* __restrict__ attnout) {
    extern __shared__ float smem[];
    float* xs   = smem;            // [256][64]
    float* qkvb = smem + 16384;    // [48][64]

    int t = threadIdx.x;
    int wv = __builtin_amdgcn_readfirstlane(t >> 6);
    int lane = t & 63;
    int widx = blockIdx.x;
    int b = widx >> 8;
    int rem = widx & 255;
    int hy = rem >> 4, wx = rem & 15;
    int y0 = hy * 8, x0 = wx * 8;
    const float* xb0 = x + (size_t)b * CCH * HWSZ + y0 * 128 + x0;

    for (int i = t; i < 4096; i += 256) {
        int ci = i >> 4;
        int q  = i & 15;
        int row = q >> 1, col = (q & 1) * 4;
        float4 v = *(const float4*)(xb0 + (size_t)ci * HWSZ + row * 128 + col);
        *(float4*)&xs[ci * 64 + q * 4] = v;
    }
    __syncthreads();

    int irow = wv * 16 + (lane & 15);
    int jg = lane >> 4;
    int iy = irow >> 3, ix = irow & 7;

    for (int h = 0; h < 16; ++h) {
        const float* wrp[12];
#pragma unroll
        for (int rr = 0; rr < 12; ++rr) {
            int r = wv * 12 + rr;
            int wr = (r >> 4) * 256 + h * 16 + (r & 15);
            wrp[rr] = qkvw + (size_t)wr * 256;
        }
        float acc12[12];
#pragma unroll
        for (int rr = 0; rr < 12; ++rr) acc12[rr] = 0.f;

        for (int ci = 0; ci < 256; ci += 4) {
            float xv0 = xs[(ci + 0) * 64 + lane];
            float xv1 = xs[(ci + 1) * 64 + lane];
            float xv2 = xs[(ci + 2) * 64 + lane];
            float xv3 = xs[(ci + 3) * 64 + lane];
#pragma unroll
            for (int rr = 0; rr < 12; ++rr) {
                float4 w = *(const float4*)(wrp[rr] + ci);
                acc12[rr] += w.x * xv0 + w.y * xv1 + w.z * xv2 + w.w * xv3;
            }
        }
        __syncthreads();
#pragma unroll
        for (int rr = 0; rr < 12; ++rr) qkvb[(wv * 12 + rr) * 64 + lane] = acc12[rr];
        __syncthreads();

        float qd[16];
#pragma unroll
        for (int d = 0; d < 16; ++d) qd[d] = qkvb[d * 64 + irow];
        float s[16];
#pragma unroll
        for (int jj = 0; jj < 16; ++jj) s[jj] = 0.f;
#pragma unroll
        for (int d = 0; d < 16; ++d) {
            const float* kp = &qkvb[(16 + d) * 64 + jg * 16];
#pragma unroll
            for (int m = 0; m < 4; ++m) {
                float4 kv = *(const float4*)(kp + m * 4);
                s[m * 4 + 0] += qd[d] * kv.x;
                s[m * 4 + 1] += qd[d] * kv.y;
                s[m * 4 + 2] += qd[d] * kv.z;
                s[m * 4 + 3] += qd[d] * kv.w;
            }
        }
#pragma unroll
        for (int jj = 0; jj < 16; ++jj) {
            int j = jg * 16 + jj;
            int jy = j >> 3, jx = j & 7;
            int rpi = (iy - jy + 7) * 15 + (ix - jx + 7);
            s[jj] = s[jj] * 0.25f + bt[rpi * 16 + h];
        }
        float mx = s[0];
#pragma unroll
        for (int jj = 1; jj < 16; ++jj) mx = fmaxf(mx, s[jj]);
        mx = fmaxf(mx, __shfl_xor(mx, 16));
        mx = fmaxf(mx, __shfl_xor(mx, 32));
        float ls = 0.f;
#pragma unroll
        for (int jj = 0; jj < 16; ++jj) { s[jj] = __expf(s[jj] - mx); ls += s[jj]; }
        ls += __shfl_xor(ls, 16);
        ls += __shfl_xor(ls, 32);
        float inv = 1.0f / ls;
#pragma unroll
        for (int d = 0; d < 16; ++d) {
            const float* vp = &qkvb[(32 + d) * 64 + jg * 16];
            float o0 = 0.f, o1 = 0.f;
#pragma unroll
            for (int m = 0; m < 4; ++m) {
                float4 vvv = *(const float4*)(vp + m * 4);
                o0 += s[m * 4 + 0] * vvv.x + s[m * 4 + 1] * vvv.y;
                o1 += s[m * 4 + 2] * vvv.z + s[m * 4 + 3] * vvv.w;
            }
            float o = o0 + o1;
            o += __shfl_xor(o, 16);
            o += __shfl_xor(o, 32);
            if (jg == 0)
                attnout[((size_t)(b * CCH + h * 16 + d)) * HWSZ + (y0 + iy) * 128 + (x0 + ix)] = o * inv;
        }
    }
}

// ---------------- dual avg-pool + add local
__global__ __launch_bounds__(256) void k_pools(const float* __restrict__ attnout, const float* __restrict__ localb,
                                               float* __restrict__ sbuf) {
    for (int i = blockIdx.x * 256 + threadIdx.x; i < 4 * CCH * HWSZ; i += gridDim.x * 256) {
        int xc = i & 127;
        int y  = (i >> 7) & 127;
        int bc = i >> 14;
        const float* pl = attnout + (size_t)bc * HWSZ;
        float axs = 0.f;
#pragma unroll
        for (int d = -3; d <= 4; ++d) {
            int t2 = y + d;
            if (t2 >= 0 && t2 < 128) axs += pl[t2 * 128 + xc];
        }
        if (y >= 124) axs += pl[126 * 128 + xc];
        float ays = 0.f;
#pragma unroll
        for (int d = -3; d <= 4; ++d) {
            int t2 = xc + d;
            if (t2 >= 0 && t2 < 128) ays += pl[y * 128 + t2];
        }
        if (xc >= 124) ays += pl[y * 128 + 126];
        sbuf[i] = (axs + ays) * 0.125f + localb[i];
    }
}

// ---------------- depthwise 8x8 (reflect +1 pad, zero pad 3) + bn
__device__ __forceinline__ void dw_loadrow(const float* __restrict__ sp, int trow, int j, float* dst) {
    if (trow < 0 || trow > 128) {
#pragma unroll
        for (int q = 0; q < 8; ++q) dst[q] = 0.f;
        return;
    }
    int sr = (trow == 128) ? 126 : trow;
    const float* rp = sp + sr * 128;
#pragma unroll
    for (int q = 0; q < 8; ++q) {
        int col = j - 3 + q;
        float v = 0.f;
        if (col >= 0 && col <= 128) v = rp[(col == 128) ? 126 : col];
        dst[q] = v;
    }
}

__global__ __launch_bounds__(256) void k_dw(const float* __restrict__ sbuf, const float* __restrict__ dww,
                                            const float* __restrict__ pscale, const float* __restrict__ pbias,
                                            float* __restrict__ tbuf) {
    int t = threadIdx.x;
    int j = t & 127;
    int half = __builtin_amdgcn_readfirstlane(t >> 7);
    int bid = blockIdx.x;
    int c = (bid & 127) * 2 + half;
    int b = bid >> 7;
    const float* sp = sbuf + ((size_t)(b * CCH + c)) * HWSZ;
    float wloc[64];
    const float* dwp = dww + c * 64;
#pragma unroll
    for (int i = 0; i < 64; ++i) wloc[i] = dwp[i];
    float scale = pscale[c], bias = pbias[c];

    float rbuf[8][8];
#pragma unroll
    for (int tr = -3; tr <= 4; ++tr) {
        dw_loadrow(sp, tr, j, rbuf[(tr + 8) & 7]);
    }
    float* op = tbuf + ((size_t)(b * CCH + c)) * HWSZ;
    for (int yb = 0; yb < 16; ++yb) {
#pragma unroll
        for (int k = 0; k < 8; ++k) {
            int y = yb * 8 + k;
            float a0 = 0.f, a1 = 0.f, a2 = 0.f, a3 = 0.f;
#pragma unroll
            for (int p = 0; p < 8; ++p) {
                const int slot = (k + 5 + p) & 7;
                float part = 0.f;
#pragma unroll
                for (int q = 0; q < 8; ++q) part += wloc[p * 8 + q] * rbuf[slot][q];
                if ((p & 3) == 0) a0 += part;
                else if ((p & 3) == 1) a1 += part;
                else if ((p & 3) == 2) a2 += part;
                else a3 += part;
            }
            op[y * 128 + j] = scale * ((a0 + a1) + (a2 + a3)) + bias;
            dw_loadrow(sp, y + 5, j, rbuf[(k + 5) & 7]);
        }
    }
}

// ---------------- pointwise 1x1 conv
__global__ __launch_bounds__(256) void k_pw(const float* __restrict__ tbuf, const float* __restrict__ pww,
                                            float* __restrict__ outp) {
    __shared__ __align__(16) float xs[8][128];
    __shared__ __align__(16) float wsm[8][64];
    int t = threadIdx.x;
    int bid = blockIdx.x;
    int cb = bid & 3;
    int row = bid >> 2;
    int y = row & 127;
    int b = row >> 7;
    int cg = t >> 4;
    int px = (t & 15) * 8;
    float acc[4][8];
#pragma unroll
    for (int c = 0; c < 4; ++c)
#pragma unroll
        for (int j = 0; j < 8; ++j) acc[c][j] = 0.f;
    const float* tb = tbuf + (size_t)b * CCH * HWSZ + y * 128;

    for (int cc = 0; cc < 32; ++cc) {
        __syncthreads();
        {
            int i = t;
#pragma unroll
            for (int it = 0; it < 4; ++it, i += 256) {
                int ci = i >> 7, p = i & 127;
                xs[ci][p] = tb[(size_t)(cc * 8 + ci) * HWSZ + p];
            }
        }
        for (int i = t; i < 512; i += 256) {
            int ci = i >> 6, co = i & 63;
            wsm[ci][co] = pww[(size_t)(cb * 64 + co) * 256 + cc * 8 + ci];
        }
        __syncthreads();
#pragma unroll
        for (int ci = 0; ci < 8; ++ci) {
            float4 w = *(const float4*)&wsm[ci][cg * 4];
            float4 xa = *(const float4*)&xs[ci][px];
            float4 xbv = *(const float4*)&xs[ci][px + 4];
            float xf[8] = {xa.x, xa.y, xa.z, xa.w, xbv.x, xbv.y, xbv.z, xbv.w};
#pragma unroll
            for (int j = 0; j < 8; ++j) {
                acc[0][j] += w.x * xf[j];
                acc[1][j] += w.y * xf[j];
                acc[2][j] += w.z * xf[j];
                acc[3][j] += w.w * xf[j];
            }
        }
    }
#pragma unroll
    for (int c = 0; c < 4; ++c) {
        int co = cb * 64 + cg * 4 + c;
        float* op = outp + ((size_t)(b * CCH + co)) * HWSZ + y * 128 + px;
        *(float4*)op = make_float4(acc[c][0], acc[c][1], acc[c][2], acc[c][3]);
        *(float4*)(op + 4) = make_float4(acc[c][4], acc[c][5], acc[c][6], acc[c][7]);
    }
}

extern "C" void kernel_launch(void* const* d_in, const int* in_sizes, int n_in,
                              void* d_out, int out_size, void* d_ws, size_t ws_size,
                              hipStream_t stream) {
    const float* x    = (const float*)d_in[0];
    const float* qkvw = (const float*)d_in[1];
    const float* l1w  = (const float*)d_in[2];
    const float* l1s  = (const float*)d_in[3];
    const float* l1b  = (const float*)d_in[4];
    const float* l2w  = (const float*)d_in[5];
    const float* l2s  = (const float*)d_in[6];
    const float* l2b  = (const float*)d_in[7];
    const float* dww  = (const float*)d_in[8];
    const float* ps   = (const float*)d_in[9];
    const float* pb   = (const float*)d_in[10];
    const float* pww  = (const float*)d_in[11];
    const float* bt   = (const float*)d_in[12];
    float* out = (float*)d_out;
    float* wsf = (float*)d_ws;

    const size_t nWf = 589824;          // 2304*256
    const size_t nPlane = 16777216;     // 4*256*128*128
    size_t need = (nWf + 256 + 3 * nPlane) * sizeof(float) + 2 * 589824 * sizeof(ushort);
    if (ws_size < need) return;

    float* Wf      = wsf;
    float* biasf   = wsf + nWf;
    float* attnout = wsf + nWf + 256;
    float* localb  = attnout + nPlane;
    float* sbuf    = localb + nPlane;
    float* tbuf    = attnout;                 // attnout dead after k_pools
    // xT planes alias sbuf (dead until k_pools writes it)
    ushort* xhi = (ushort*)sbuf;              // nPlane ushorts
    ushort* xlo = xhi + nPlane;               // nPlane ushorts (= rest of sbuf)
    ushort* ahi = (ushort*)(sbuf + nPlane);   // after sbuf
    ushort* alo = ahi + 589824;

    const int attn_lds = (16384 + 3072) * sizeof(float);
    hipFuncSetAttribute((const void*)k_attn, hipFuncAttributeMaxDynamicSharedMemorySize, attn_lds);

    k_fold  <<<2304, 256, 0, stream>>>(l1w, l1s, l1b, l2w, l2s, l2b, Wf, biasf);
    k_wsplit<<<2304, 256, 0, stream>>>(Wf, ahi, alo);
    k_cvt   <<<2048, 256, 0, stream>>>(x, xhi, xlo);
    k_conv3m<<<1024, 256, 0, stream>>>(xhi, xlo, ahi, alo, biasf, localb);
    k_attn  <<<1024, 256, attn_lds, stream>>>(x, qkvw, bt, attnout);
    k_pools <<<4096, 256, 0, stream>>>(attnout, localb, sbuf);
    k_dw    <<<512,  256, 0, stream>>>(sbuf, dww, ps, pb, tbuf);
    k_pw    <<<2048, 256, 0, stream>>>(tbuf, pww, out);
}

// Round 4
// 932.864 us; speedup vs baseline: 3.4121x; 2.0127x over previous
//
#include <hip/hip_runtime.h>
#include <cstddef>

#define HH 128
#define WW2 128
#define HWSZ (HH*WW2)
#define CCH 256

typedef __attribute__((ext_vector_type(8))) short short8v;   // 8 bf16 = 4 VGPR
typedef __attribute__((ext_vector_type(16))) float f32x16;   // MFMA 32x32 acc
typedef __attribute__((ext_vector_type(4)))  float f32x4;    // MFMA 16x16 acc

__device__ __forceinline__ ushort bf16rte(float v) {
    uint u = __float_as_uint(v);
    uint r = u + 0x7FFFu + ((u >> 16) & 1u);
    return (ushort)(r >> 16);
}

// ---------------- fold: Wf[ci*9+k][co] = l1s*l1w (+ center: l2s*l2w); biasf = l1b+l2b
__global__ __launch_bounds__(256) void k_fold(const float* __restrict__ l1w, const float* __restrict__ l1s,
                                              const float* __restrict__ l1b, const float* __restrict__ l2w,
                                              const float* __restrict__ l2s, const float* __restrict__ l2b,
                                              float* __restrict__ Wf, float* __restrict__ biasf) {
    int idx = blockIdx.x * 256 + threadIdx.x;
    if (idx < 2304 * 256) {
        int co = idx & 255;
        int i2 = idx >> 8;           // 0..2303 = ci*9+k
        int ci = i2 / 9;
        int k  = i2 - ci * 9;
        float w = l1s[co] * l1w[co * 2304 + ci * 9 + k];
        if (k == 4) w += l2s[co] * l2w[co * 256 + ci];
        Wf[i2 * 256 + co] = w;
    }
    if (idx < 256) biasf[idx] = l1b[idx] + l2b[idx];
}

// ---------------- conv weight split into 32x32 A-fragment order, hi/lo bf16 planes
__global__ __launch_bounds__(256) void k_wsplit(const float* __restrict__ Wf,
                                                ushort* __restrict__ ahi, ushort* __restrict__ alo) {
    int idx = blockIdx.x * 256 + threadIdx.x;     // 589824 total
    if (idx >= 589824) return;
    int j    = idx & 7;
    int lane = (idx >> 3) & 63;
    int t2   = idx >> 9;
    int kb   = t2 % 144;
    int cob  = t2 / 144;
    int cc  = kb / 18; int rem = kb - cc * 18; int tap = rem >> 1; int ks = rem & 1;
    int ci  = cc * 32 + ks * 16 + ((lane >> 5) << 3) + j;
    int co  = cob * 32 + (lane & 31);
    float v = Wf[(size_t)(ci * 9 + tap) * 256 + co];
    ushort h = bf16rte(v);
    float hf = __uint_as_float((uint)h << 16);
    ushort l = bf16rte(v - hf);
    ahi[idx] = h;
    alo[idx] = l;
}

// ---------------- qkv weight split into 16x16x32 A-fragment order, hi/lo planes
// layout: [(h*3+p)*8+kk][lane][8j]; co = p*256+h*16+(lane&15); ci = kk*32+(lane>>4)*8+j
__global__ __launch_bounds__(256) void k_aswz(const float* __restrict__ qkvw,
                                              ushort* __restrict__ aqh, ushort* __restrict__ aql) {
    int idx = blockIdx.x * 256 + threadIdx.x;     // 196608 total
    if (idx >= 196608) return;
    int j    = idx & 7;
    int lane = (idx >> 3) & 63;
    int t2   = idx >> 9;          // 0..383 = (h*3+p)*8+kk
    int kk   = t2 & 7;
    int hp   = t2 >> 3;           // h*3+p
    int p    = hp % 3, h = hp / 3;
    int co = p * 256 + h * 16 + (lane & 15);
    int ci = kk * 32 + ((lane >> 4) << 3) + j;
    float v = qkvw[(size_t)co * 256 + ci];
    ushort hi = bf16rte(v);
    float hf = __uint_as_float((uint)hi << 16);
    aqh[idx] = hi;
    aql[idx] = bf16rte(v - hf);
}

// ---------------- x -> pixel-major bf16 hi/lo planes: xT[b][pix][256ci]
__global__ __launch_bounds__(256) void k_cvt(const float* __restrict__ x,
                                             ushort* __restrict__ xhi, ushort* __restrict__ xlo) {
    __shared__ uint pk[32 * 265];
    int t = threadIdx.x;
    int bid = blockIdx.x;               // 4 * 512
    int b = bid >> 9;
    int px0 = (bid & 511) * 32;
    const float* xb = x + (size_t)b * CCH * HWSZ;
    for (int step = 0; step < 32; ++step) {
        int ci = step * 8 + (t >> 5);
        float v = xb[(size_t)ci * HWSZ + px0 + (t & 31)];
        ushort h = bf16rte(v);
        float hf = __uint_as_float((uint)h << 16);
        ushort l = bf16rte(v - hf);
        pk[(t & 31) * 265 + ci] = ((uint)h << 16) | l;
    }
    __syncthreads();
    int pxl = t >> 3, o = t & 7;
    uint* hp = (uint*)xhi;
    uint* lp = (uint*)xlo;
    size_t pb2 = ((size_t)b * HWSZ + px0 + pxl) * 128;
#pragma unroll
    for (int m = 0; m < 16; ++m) {
        int cip = m * 16 + o * 2;
        uint p0 = pk[pxl * 265 + cip];
        uint p1 = pk[pxl * 265 + cip + 1];
        hp[pb2 + m * 8 + o] = (p1 & 0xFFFF0000u) | (p0 >> 16);
        lp[pb2 + m * 8 + o] = (p1 << 16) | (p0 & 0xFFFFu);
    }
}

// ---------------- conv3x3 as implicit GEMM via mfma_f32_32x32x16_bf16 (3-term split)
__global__ __launch_bounds__(256) void k_conv3m(const ushort* __restrict__ xhi, const ushort* __restrict__ xlo,
                                                const ushort* __restrict__ afr_hi, const ushort* __restrict__ afr_lo,
                                                const float* __restrict__ biasf, float* __restrict__ outp) {
    __shared__ __align__(16) ushort Xsh[12960];   // hi at byte 0, lo at byte 12960
    char* xsb = (char*)Xsh;

    int t = threadIdx.x;
    int bid = blockIdx.x;
    int cb = bid & 1;
    int t2 = bid >> 1;
    int tile_c = t2 & 7;
    int tile_r = (t2 >> 3) & 15;
    int b = t2 >> 7;
    int x0 = tile_c * 16, y0 = tile_r * 8;

    int w = t >> 6, lane = t & 63;
    int co_w = cb * 128 + (w >> 1) * 64;
    int pr0 = (w & 1) * 4;
    int pr_l = (lane & 31) >> 4;
    int pc = lane & 15;
    int kl = lane >> 5;
    int lb0 = (pr0 + 0 + pr_l) * 1296 + pc * 72 + kl * 16;
    int lb1 = (pr0 + 2 + pr_l) * 1296 + pc * 72 + kl * 16;

    const short8v* Ahi = (const short8v*)afr_hi;
    const short8v* Alo = (const short8v*)afr_lo;
    int cobase = (co_w >> 5) * 144 * 64;

    f32x16 c00 = {}, c01 = {}, c10 = {}, c11 = {};

    for (int cc = 0; cc < 8; ++cc) {
        __syncthreads();
#pragma unroll
        for (int it = 0; it < 6; ++it) {
            int i = t + it * 256;
            if (i < 1440) {
                int oct = i & 3;
                int j2 = i >> 2;
                int plane = j2 & 1;
                int loc = j2 >> 1;
                int r = loc / 18, c = loc - r * 18;
                int gy = y0 - 1 + r, gx = x0 - 1 + c;
                uint4 v = make_uint4(0u, 0u, 0u, 0u);
                if (gy >= 0 && gy < 128 && gx >= 0 && gx < 128) {
                    const ushort* src = plane ? xlo : xhi;
                    v = *(const uint4*)(src + ((size_t)(b * HWSZ + gy * 128 + gx) * 256 + cc * 32 + oct * 8));
                }
                *(uint4*)(xsb + plane * 12960 + loc * 72 + oct * 16) = v;
            }
        }
        __syncthreads();

        int baseA = cobase + cc * 18 * 64 + lane;
#pragma unroll
        for (int tap = 0; tap < 9; ++tap) {
            const int ky = tap / 3, kx = tap - ky * 3;
#pragma unroll
            for (int ks = 0; ks < 2; ++ks) {
                const int boff = ky * 1296 + kx * 72 + ks * 32;
                short8v b0h = *(const short8v*)(xsb + lb0 + boff);
                short8v b0l = *(const short8v*)(xsb + lb0 + boff + 12960);
                short8v b1h = *(const short8v*)(xsb + lb1 + boff);
                short8v b1l = *(const short8v*)(xsb + lb1 + boff + 12960);
                int ai = baseA + (tap * 2 + ks) * 64;
                short8v a0h = Ahi[ai];
                short8v a0l = Alo[ai];
                short8v a1h = Ahi[ai + 144 * 64];
                short8v a1l = Alo[ai + 144 * 64];
                c00 = __builtin_amdgcn_mfma_f32_32x32x16_bf16(a0h, b0h, c00, 0, 0, 0);
                c00 = __builtin_amdgcn_mfma_f32_32x32x16_bf16(a0h, b0l, c00, 0, 0, 0);
                c00 = __builtin_amdgcn_mfma_f32_32x32x16_bf16(a0l, b0h, c00, 0, 0, 0);
                c01 = __builtin_amdgcn_mfma_f32_32x32x16_bf16(a0h, b1h, c01, 0, 0, 0);
                c01 = __builtin_amdgcn_mfma_f32_32x32x16_bf16(a0h, b1l, c01, 0, 0, 0);
                c01 = __builtin_amdgcn_mfma_f32_32x32x16_bf16(a0l, b1h, c01, 0, 0, 0);
                c10 = __builtin_amdgcn_mfma_f32_32x32x16_bf16(a1h, b0h, c10, 0, 0, 0);
                c10 = __builtin_amdgcn_mfma_f32_32x32x16_bf16(a1h, b0l, c10, 0, 0, 0);
                c10 = __builtin_amdgcn_mfma_f32_32x32x16_bf16(a1l, b0h, c10, 0, 0, 0);
                c11 = __builtin_amdgcn_mfma_f32_32x32x16_bf16(a1h, b1h, c11, 0, 0, 0);
                c11 = __builtin_amdgcn_mfma_f32_32x32x16_bf16(a1h, b1l, c11, 0, 0, 0);
                c11 = __builtin_amdgcn_mfma_f32_32x32x16_bf16(a1l, b1h, c11, 0, 0, 0);
            }
        }
    }

    int colg = x0 + pc;
    int row0 = y0 + pr0 + pr_l;
    int row1 = row0 + 2;
#pragma unroll
    for (int r = 0; r < 16; ++r) {
        int rr = (r & 3) + 8 * (r >> 2) + 4 * kl;
        {
            int co = co_w + rr;
            float bv = biasf[co];
            float* ob = outp + ((size_t)(b * CCH + co)) * HWSZ;
            ob[row0 * 128 + colg] = c00[r] + bv;
            ob[row1 * 128 + colg] = c01[r] + bv;
        }
        {
            int co = co_w + 32 + rr;
            float bv = biasf[co];
            float* ob = outp + ((size_t)(b * CCH + co)) * HWSZ;
            ob[row0 * 128 + colg] = c10[r] + bv;
            ob[row1 * 128 + colg] = c11[r] + bv;
        }
    }
}

// ---------------- fused qkv(MFMA) + window attention: one WG per 8x8 window
// LDS: Bs = x-window B-fragments [2 plane][4 tt][8 kk][64 lane][8] bf16 (64 KB)
//      qkvb = [48][64] fp32 (12 KB)
__global__ __launch_bounds__(256) void k_attn(const ushort* __restrict__ xhi, const ushort* __restrict__ xlo,
                                              const ushort* __restrict__ aqh, const ushort* __restrict__ aql,
                                              const float* __restrict__ bt, float* __restrict__ attnout) {
    extern __shared__ float smem[];
    ushort* Bs  = (ushort*)smem;       // 32768 ushorts
    float* qkvb = smem + 16384;        // [48][64]

    int t = threadIdx.x;
    int wv = __builtin_amdgcn_readfirstlane(t >> 6);
    int lane = t & 63;
    int widx = blockIdx.x;
    int b = widx >> 8;
    int rem = widx & 255;
    int hy = rem >> 4, wx = rem & 15;
    int y0 = hy * 8, x0 = wx * 8;

    // ---- stage B fragments (x window, both planes) into LDS in frag order
#pragma unroll
    for (int it = 0; it < 16; ++it) {
        int i = it * 256 + t;
        int plane = i >> 11;
        int r2 = i & 2047;
        int tok = r2 >> 5, ci8 = r2 & 31;
        int pix = (y0 + (tok >> 3)) * 128 + (x0 + (tok & 7));
        const ushort* src = plane ? xlo : xhi;
        uint4 v = *(const uint4*)(src + ((size_t)b * HWSZ + pix) * 256 + ci8 * 8);
        int lane2 = ((ci8 & 3) << 4) | (tok & 15);
        int fragid = (plane * 4 + (tok >> 4)) * 8 + (ci8 >> 2);
        *(uint4*)(Bs + (size_t)(fragid * 64 + lane2) * 8) = v;
    }
    __syncthreads();

    int irow = wv * 16 + (lane & 15);
    int jg = lane >> 4;
    int iy = irow >> 3, ix = irow & 7;
    int g0 = wv * 3;                    // this wave's 3 output tiles (of 12)

    for (int h = 0; h < 16; ++h) {
        // ---- qkv MFMA: tile gid = p*4+tt; wave handles gid = g0..g0+2
        f32x4 c0 = {}, c1 = {}, c2 = {};
#pragma unroll
        for (int g = 0; g < 3; ++g) {
            int gid = g0 + g;
            int p = gid >> 2, tt = gid & 3;
            const short8v* Ah = (const short8v*)aqh + (size_t)((h * 3 + p) * 8) * 64 + lane;
            const short8v* Al = (const short8v*)aql + (size_t)((h * 3 + p) * 8) * 64 + lane;
            const short8v* Bh = (const short8v*)Bs + (tt * 8) * 64 + lane;
            const short8v* Bl = (const short8v*)Bs + ((4 + tt) * 8) * 64 + lane;
            f32x4 c = {};
#pragma unroll
            for (int kk = 0; kk < 8; ++kk) {
                short8v ah = Ah[kk * 64], al = Al[kk * 64];
                short8v bh = Bh[kk * 64], bl = Bl[kk * 64];
                c = __builtin_amdgcn_mfma_f32_16x16x32_bf16(ah, bh, c, 0, 0, 0);
                c = __builtin_amdgcn_mfma_f32_16x16x32_bf16(ah, bl, c, 0, 0, 0);
                c = __builtin_amdgcn_mfma_f32_16x16x32_bf16(al, bh, c, 0, 0, 0);
            }
            if (g == 0) c0 = c; else if (g == 1) c1 = c; else c2 = c;
        }
        __syncthreads();   // prior-head attention reads of qkvb done
#pragma unroll
        for (int g = 0; g < 3; ++g) {
            int gid = g0 + g;
            int p = gid >> 2, tt = gid & 3;
            int tok = tt * 16 + (lane & 15);
            int row0 = (lane >> 4) * 4;
            f32x4 c = (g == 0) ? c0 : (g == 1) ? c1 : c2;
#pragma unroll
            for (int r = 0; r < 4; ++r)
                qkvb[(p * 16 + row0 + r) * 64 + tok] = c[r];
        }
        __syncthreads();

        // ---- attention: row irow, j-range jg*16..jg*16+15 (fp32, unchanged)
        float qd[16];
#pragma unroll
        for (int d = 0; d < 16; ++d) qd[d] = qkvb[d * 64 + irow];
        float s[16];
#pragma unroll
        for (int jj = 0; jj < 16; ++jj) s[jj] = 0.f;
#pragma unroll
        for (int d = 0; d < 16; ++d) {
            const float* kp = &qkvb[(16 + d) * 64 + jg * 16];
#pragma unroll
            for (int m = 0; m < 4; ++m) {
                float4 kv = *(const float4*)(kp + m * 4);
                s[m * 4 + 0] += qd[d] * kv.x;
                s[m * 4 + 1] += qd[d] * kv.y;
                s[m * 4 + 2] += qd[d] * kv.z;
                s[m * 4 + 3] += qd[d] * kv.w;
            }
        }
#pragma unroll
        for (int jj = 0; jj < 16; ++jj) {
            int j = jg * 16 + jj;
            int jy = j >> 3, jx = j & 7;
            int rpi = (iy - jy + 7) * 15 + (ix - jx + 7);
            s[jj] = s[jj] * 0.25f + bt[rpi * 16 + h];
        }
        float mx = s[0];
#pragma unroll
        for (int jj = 1; jj < 16; ++jj) mx = fmaxf(mx, s[jj]);
        mx = fmaxf(mx, __shfl_xor(mx, 16));
        mx = fmaxf(mx, __shfl_xor(mx, 32));
        float ls = 0.f;
#pragma unroll
        for (int jj = 0; jj < 16; ++jj) { s[jj] = __expf(s[jj] - mx); ls += s[jj]; }
        ls += __shfl_xor(ls, 16);
        ls += __shfl_xor(ls, 32);
        float inv = 1.0f / ls;
#pragma unroll
        for (int d = 0; d < 16; ++d) {
            const float* vp = &qkvb[(32 + d) * 64 + jg * 16];
            float o0 = 0.f, o1 = 0.f;
#pragma unroll
            for (int m = 0; m < 4; ++m) {
                float4 vvv = *(const float4*)(vp + m * 4);
                o0 += s[m * 4 + 0] * vvv.x + s[m * 4 + 1] * vvv.y;
                o1 += s[m * 4 + 2] * vvv.z + s[m * 4 + 3] * vvv.w;
            }
            float o = o0 + o1;
            o += __shfl_xor(o, 16);
            o += __shfl_xor(o, 32);
            if (jg == 0)
                attnout[((size_t)(b * CCH + h * 16 + d)) * HWSZ + (y0 + iy) * 128 + (x0 + ix)] = o * inv;
        }
    }
}

// ---------------- dual avg-pool + add local
__global__ __launch_bounds__(256) void k_pools(const float* __restrict__ attnout, const float* __restrict__ localb,
                                               float* __restrict__ sbuf) {
    for (int i = blockIdx.x * 256 + threadIdx.x; i < 4 * CCH * HWSZ; i += gridDim.x * 256) {
        int xc = i & 127;
        int y  = (i >> 7) & 127;
        int bc = i >> 14;
        const float* pl = attnout + (size_t)bc * HWSZ;
        float axs = 0.f;
#pragma unroll
        for (int d = -3; d <= 4; ++d) {
            int t2 = y + d;
            if (t2 >= 0 && t2 < 128) axs += pl[t2 * 128 + xc];
        }
        if (y >= 124) axs += pl[126 * 128 + xc];
        float ays = 0.f;
#pragma unroll
        for (int d = -3; d <= 4; ++d) {
            int t2 = xc + d;
            if (t2 >= 0 && t2 < 128) ays += pl[y * 128 + t2];
        }
        if (xc >= 124) ays += pl[y * 128 + 126];
        sbuf[i] = (axs + ays) * 0.125f + localb[i];
    }
}

// ---------------- depthwise 8x8 (reflect +1 pad, zero pad 3) + bn
__device__ __forceinline__ void dw_loadrow(const float* __restrict__ sp, int trow, int j, float* dst) {
    if (trow < 0 || trow > 128) {
#pragma unroll
        for (int q = 0; q < 8; ++q) dst[q] = 0.f;
        return;
    }
    int sr = (trow == 128) ? 126 : trow;
    const float* rp = sp + sr * 128;
#pragma unroll
    for (int q = 0; q < 8; ++q) {
        int col = j - 3 + q;
        float v = 0.f;
        if (col >= 0 && col <= 128) v = rp[(col == 128) ? 126 : col];
        dst[q] = v;
    }
}

__global__ __launch_bounds__(256) void k_dw(const float* __restrict__ sbuf, const float* __restrict__ dww,
                                            const float* __restrict__ pscale, const float* __restrict__ pbias,
                                            float* __restrict__ tbuf) {
    int t = threadIdx.x;
    int j = t & 127;
    int half = __builtin_amdgcn_readfirstlane(t >> 7);
    int bid = blockIdx.x;
    int c = (bid & 127) * 2 + half;
    int b = bid >> 7;
    const float* sp = sbuf + ((size_t)(b * CCH + c)) * HWSZ;
    float wloc[64];
    const float* dwp = dww + c * 64;
#pragma unroll
    for (int i = 0; i < 64; ++i) wloc[i] = dwp[i];
    float scale = pscale[c], bias = pbias[c];

    float rbuf[8][8];
#pragma unroll
    for (int tr = -3; tr <= 4; ++tr) {
        dw_loadrow(sp, tr, j, rbuf[(tr + 8) & 7]);
    }
    float* op = tbuf + ((size_t)(b * CCH + c)) * HWSZ;
    for (int yb = 0; yb < 16; ++yb) {
#pragma unroll
        for (int k = 0; k < 8; ++k) {
            int y = yb * 8 + k;
            float a0 = 0.f, a1 = 0.f, a2 = 0.f, a3 = 0.f;
#pragma unroll
            for (int p = 0; p < 8; ++p) {
                const int slot = (k + 5 + p) & 7;
                float part = 0.f;
#pragma unroll
                for (int q = 0; q < 8; ++q) part += wloc[p * 8 + q] * rbuf[slot][q];
                if ((p & 3) == 0) a0 += part;
                else if ((p & 3) == 1) a1 += part;
                else if ((p & 3) == 2) a2 += part;
                else a3 += part;
            }
            op[y * 128 + j] = scale * ((a0 + a1) + (a2 + a3)) + bias;
            dw_loadrow(sp, y + 5, j, rbuf[(k + 5) & 7]);
        }
    }
}

// ---------------- pointwise 1x1 conv
__global__ __launch_bounds__(256) void k_pw(const float* __restrict__ tbuf, const float* __restrict__ pww,
                                            float* __restrict__ outp) {
    __shared__ __align__(16) float xs[8][128];
    __shared__ __align__(16) float wsm[8][64];
    int t = threadIdx.x;
    int bid = blockIdx.x;
    int cb = bid & 3;
    int row = bid >> 2;
    int y = row & 127;
    int b = row >> 7;
    int cg = t >> 4;
    int px = (t & 15) * 8;
    float acc[4][8];
#pragma unroll
    for (int c = 0; c < 4; ++c)
#pragma unroll
        for (int j = 0; j < 8; ++j) acc[c][j] = 0.f;
    const float* tb = tbuf + (size_t)b * CCH * HWSZ + y * 128;

    for (int cc = 0; cc < 32; ++cc) {
        __syncthreads();
        {
            int i = t;
#pragma unroll
            for (int it = 0; it < 4; ++it, i += 256) {
                int ci = i >> 7, p = i & 127;
                xs[ci][p] = tb[(size_t)(cc * 8 + ci) * HWSZ + p];
            }
        }
        for (int i = t; i < 512; i += 256) {
            int ci = i >> 6, co = i & 63;
            wsm[ci][co] = pww[(size_t)(cb * 64 + co) * 256 + cc * 8 + ci];
        }
        __syncthreads();
#pragma unroll
        for (int ci = 0; ci < 8; ++ci) {
            float4 w = *(const float4*)&wsm[ci][cg * 4];
            float4 xa = *(const float4*)&xs[ci][px];
            float4 xbv = *(const float4*)&xs[ci][px + 4];
            float xf[8] = {xa.x, xa.y, xa.z, xa.w, xbv.x, xbv.y, xbv.z, xbv.w};
#pragma unroll
            for (int j = 0; j < 8; ++j) {
                acc[0][j] += w.x * xf[j];
                acc[1][j] += w.y * xf[j];
                acc[2][j] += w.z * xf[j];
                acc[3][j] += w.w * xf[j];
            }
        }
    }
#pragma unroll
    for (int c = 0; c < 4; ++c) {
        int co = cb * 64 + cg * 4 + c;
        float* op = outp + ((size_t)(b * CCH + co)) * HWSZ + y * 128 + px;
        *(float4*)op = make_float4(acc[c][0], acc[c][1], acc[c][2], acc[c][3]);
        *(float4*)(op + 4) = make_float4(acc[c][4], acc[c][5], acc[c][6], acc[c][7]);
    }
}

extern "C" void kernel_launch(void* const* d_in, const int* in_sizes, int n_in,
                              void* d_out, int out_size, void* d_ws, size_t ws_size,
                              hipStream_t stream) {
    const float* x    = (const float*)d_in[0];
    const float* qkvw = (const float*)d_in[1];
    const float* l1w  = (const float*)d_in[2];
    const float* l1s  = (const float*)d_in[3];
    const float* l1b  = (const float*)d_in[4];
    const float* l2w  = (const float*)d_in[5];
    const float* l2s  = (const float*)d_in[6];
    const float* l2b  = (const float*)d_in[7];
    const float* dww  = (const float*)d_in[8];
    const float* ps   = (const float*)d_in[9];
    const float* pb   = (const float*)d_in[10];
    const float* pww  = (const float*)d_in[11];
    const float* bt   = (const float*)d_in[12];
    float* out = (float*)d_out;
    float* wsf = (float*)d_ws;

    const size_t nWf = 589824;          // 2304*256
    const size_t nPlane = 16777216;     // 4*256*128*128
    const size_t nAq = 196608;          // 16*3*8*64*8
    size_t need = (nWf + 256 + 3 * nPlane) * sizeof(float) + (2 * 589824 + 2 * nAq) * sizeof(ushort);
    if (ws_size < need) return;

    float* Wf      = wsf;
    float* biasf   = wsf + nWf;
    float* attnout = wsf + nWf + 256;
    float* localb  = attnout + nPlane;
    float* sbuf    = localb + nPlane;
    float* tbuf    = attnout;                 // attnout dead after k_pools
    ushort* xhi = (ushort*)sbuf;              // aliases sbuf (dead until k_pools)
    ushort* xlo = xhi + nPlane;
    ushort* ahi = (ushort*)(sbuf + nPlane);   // after sbuf region
    ushort* alo = ahi + 589824;
    ushort* aqh = alo + 589824;
    ushort* aql = aqh + nAq;

    const int attn_lds = 65536 + 12288;       // Bs + qkvb
    hipFuncSetAttribute((const void*)k_attn, hipFuncAttributeMaxDynamicSharedMemorySize, attn_lds);

    k_fold  <<<2304, 256, 0, stream>>>(l1w, l1s, l1b, l2w, l2s, l2b, Wf, biasf);
    k_wsplit<<<2304, 256, 0, stream>>>(Wf, ahi, alo);
    k_aswz  <<<768,  256, 0, stream>>>(qkvw, aqh, aql);
    k_cvt   <<<2048, 256, 0, stream>>>(x, xhi, xlo);
    k_conv3m<<<1024, 256, 0, stream>>>(xhi, xlo, ahi, alo, biasf, localb);
    k_attn  <<<1024, 256, attn_lds, stream>>>(xhi, xlo, aqh, aql, bt, attnout);
    k_pools <<<4096, 256, 0, stream>>>(attnout, localb, sbuf);
    k_dw    <<<512,  256, 0, stream>>>(sbuf, dww, ps, pb, tbuf);
    k_pw    <<<2048, 256, 0, stream>>>(tbuf, pww, out);
}

// Round 5
// 884.249 us; speedup vs baseline: 3.5997x; 1.0550x over previous
//
#include <hip/hip_runtime.h>
#include <cstddef>

#define HH 128
#define WW2 128
#define HWSZ (HH*WW2)
#define CCH 256

typedef __attribute__((ext_vector_type(8))) short short8v;   // 8 bf16 = 4 VGPR
typedef __attribute__((ext_vector_type(16))) float f32x16;   // MFMA 32x32 acc
typedef __attribute__((ext_vector_type(4)))  float f32x4;    // MFMA 16x16 acc

__device__ __forceinline__ ushort bf16rte(float v) {
    uint u = __float_as_uint(v);
    uint r = u + 0x7FFFu + ((u >> 16) & 1u);
    return (ushort)(r >> 16);
}

// ---------------- fold: Wf[ci*9+k][co] = l1s*l1w (+ center: l2s*l2w); biasf = l1b+l2b
__global__ __launch_bounds__(256) void k_fold(const float* __restrict__ l1w, const float* __restrict__ l1s,
                                              const float* __restrict__ l1b, const float* __restrict__ l2w,
                                              const float* __restrict__ l2s, const float* __restrict__ l2b,
                                              float* __restrict__ Wf, float* __restrict__ biasf) {
    int idx = blockIdx.x * 256 + threadIdx.x;
    if (idx < 2304 * 256) {
        int co = idx & 255;
        int i2 = idx >> 8;           // 0..2303 = ci*9+k
        int ci = i2 / 9;
        int k  = i2 - ci * 9;
        float w = l1s[co] * l1w[co * 2304 + ci * 9 + k];
        if (k == 4) w += l2s[co] * l2w[co * 256 + ci];
        Wf[i2 * 256 + co] = w;
    }
    if (idx < 256) biasf[idx] = l1b[idx] + l2b[idx];
}

// ---------------- conv weight split into 32x32 A-fragment order, hi/lo bf16 planes
__global__ __launch_bounds__(256) void k_wsplit(const float* __restrict__ Wf,
                                                ushort* __restrict__ ahi, ushort* __restrict__ alo) {
    int idx = blockIdx.x * 256 + threadIdx.x;     // 589824 total
    if (idx >= 589824) return;
    int j    = idx & 7;
    int lane = (idx >> 3) & 63;
    int t2   = idx >> 9;
    int kb   = t2 % 144;
    int cob  = t2 / 144;
    int cc  = kb / 18; int rem = kb - cc * 18; int tap = rem >> 1; int ks = rem & 1;
    int ci  = cc * 32 + ks * 16 + ((lane >> 5) << 3) + j;
    int co  = cob * 32 + (lane & 31);
    float v = Wf[(size_t)(ci * 9 + tap) * 256 + co];
    ushort h = bf16rte(v);
    float hf = __uint_as_float((uint)h << 16);
    ushort l = bf16rte(v - hf);
    ahi[idx] = h;
    alo[idx] = l;
}

// ---------------- qkv weight split into 16x16x32 A-fragment order, hi/lo planes
// layout: [(h*3+p)*8+kk][lane][8j]; co = p*256+h*16+(lane&15); ci = kk*32+(lane>>4)*8+j
__global__ __launch_bounds__(256) void k_aswz(const float* __restrict__ qkvw,
                                              ushort* __restrict__ aqh, ushort* __restrict__ aql) {
    int idx = blockIdx.x * 256 + threadIdx.x;     // 196608 total
    if (idx >= 196608) return;
    int j    = idx & 7;
    int lane = (idx >> 3) & 63;
    int t2   = idx >> 9;          // 0..383 = (h*3+p)*8+kk
    int kk   = t2 & 7;
    int hp   = t2 >> 3;           // h*3+p
    int p    = hp % 3, h = hp / 3;
    int co = p * 256 + h * 16 + (lane & 15);
    int ci = kk * 32 + ((lane >> 4) << 3) + j;
    float v = qkvw[(size_t)co * 256 + ci];
    ushort hi = bf16rte(v);
    float hf = __uint_as_float((uint)hi << 16);
    aqh[idx] = hi;
    aql[idx] = bf16rte(v - hf);
}

// ---------------- x -> pixel-major bf16 hi/lo planes: xT[b][pix][256ci]
__global__ __launch_bounds__(256) void k_cvt(const float* __restrict__ x,
                                             ushort* __restrict__ xhi, ushort* __restrict__ xlo) {
    __shared__ uint pk[32 * 265];
    int t = threadIdx.x;
    int bid = blockIdx.x;               // 4 * 512
    int b = bid >> 9;
    int px0 = (bid & 511) * 32;
    const float* xb = x + (size_t)b * CCH * HWSZ;
    for (int step = 0; step < 32; ++step) {
        int ci = step * 8 + (t >> 5);
        float v = xb[(size_t)ci * HWSZ + px0 + (t & 31)];
        ushort h = bf16rte(v);
        float hf = __uint_as_float((uint)h << 16);
        ushort l = bf16rte(v - hf);
        pk[(t & 31) * 265 + ci] = ((uint)h << 16) | l;
    }
    __syncthreads();
    int pxl = t >> 3, o = t & 7;
    uint* hp = (uint*)xhi;
    uint* lp = (uint*)xlo;
    size_t pb2 = ((size_t)b * HWSZ + px0 + pxl) * 128;
#pragma unroll
    for (int m = 0; m < 16; ++m) {
        int cip = m * 16 + o * 2;
        uint p0 = pk[pxl * 265 + cip];
        uint p1 = pk[pxl * 265 + cip + 1];
        hp[pb2 + m * 8 + o] = (p1 & 0xFFFF0000u) | (p0 >> 16);
        lp[pb2 + m * 8 + o] = (p1 << 16) | (p0 & 0xFFFFu);
    }
}

// ---------------- conv3x3 as implicit GEMM via mfma_f32_32x32x16_bf16 (3-term split)
__global__ __launch_bounds__(256) void k_conv3m(const ushort* __restrict__ xhi, const ushort* __restrict__ xlo,
                                                const ushort* __restrict__ afr_hi, const ushort* __restrict__ afr_lo,
                                                const float* __restrict__ biasf, float* __restrict__ outp) {
    __shared__ __align__(16) ushort Xsh[12960];   // hi at byte 0, lo at byte 12960
    char* xsb = (char*)Xsh;

    int t = threadIdx.x;
    int bid = blockIdx.x;
    int cb = bid & 1;
    int t2 = bid >> 1;
    int tile_c = t2 & 7;
    int tile_r = (t2 >> 3) & 15;
    int b = t2 >> 7;
    int x0 = tile_c * 16, y0 = tile_r * 8;

    int w = t >> 6, lane = t & 63;
    int co_w = cb * 128 + (w >> 1) * 64;
    int pr0 = (w & 1) * 4;
    int pr_l = (lane & 31) >> 4;
    int pc = lane & 15;
    int kl = lane >> 5;
    int lb0 = (pr0 + 0 + pr_l) * 1296 + pc * 72 + kl * 16;
    int lb1 = (pr0 + 2 + pr_l) * 1296 + pc * 72 + kl * 16;

    const short8v* Ahi = (const short8v*)afr_hi;
    const short8v* Alo = (const short8v*)afr_lo;
    int cobase = (co_w >> 5) * 144 * 64;

    f32x16 c00 = {}, c01 = {}, c10 = {}, c11 = {};

    for (int cc = 0; cc < 8; ++cc) {
        __syncthreads();
#pragma unroll
        for (int it = 0; it < 6; ++it) {
            int i = t + it * 256;
            if (i < 1440) {
                int oct = i & 3;
                int j2 = i >> 2;
                int plane = j2 & 1;
                int loc = j2 >> 1;
                int r = loc / 18, c = loc - r * 18;
                int gy = y0 - 1 + r, gx = x0 - 1 + c;
                uint4 v = make_uint4(0u, 0u, 0u, 0u);
                if (gy >= 0 && gy < 128 && gx >= 0 && gx < 128) {
                    const ushort* src = plane ? xlo : xhi;
                    v = *(const uint4*)(src + ((size_t)(b * HWSZ + gy * 128 + gx) * 256 + cc * 32 + oct * 8));
                }
                *(uint4*)(xsb + plane * 12960 + loc * 72 + oct * 16) = v;
            }
        }
        __syncthreads();

        int baseA = cobase + cc * 18 * 64 + lane;
#pragma unroll
        for (int tap = 0; tap < 9; ++tap) {
            const int ky = tap / 3, kx = tap - ky * 3;
#pragma unroll
            for (int ks = 0; ks < 2; ++ks) {
                const int boff = ky * 1296 + kx * 72 + ks * 32;
                short8v b0h = *(const short8v*)(xsb + lb0 + boff);
                short8v b0l = *(const short8v*)(xsb + lb0 + boff + 12960);
                short8v b1h = *(const short8v*)(xsb + lb1 + boff);
                short8v b1l = *(const short8v*)(xsb + lb1 + boff + 12960);
                int ai = baseA + (tap * 2 + ks) * 64;
                short8v a0h = Ahi[ai];
                short8v a0l = Alo[ai];
                short8v a1h = Ahi[ai + 144 * 64];
                short8v a1l = Alo[ai + 144 * 64];
                c00 = __builtin_amdgcn_mfma_f32_32x32x16_bf16(a0h, b0h, c00, 0, 0, 0);
                c00 = __builtin_amdgcn_mfma_f32_32x32x16_bf16(a0h, b0l, c00, 0, 0, 0);
                c00 = __builtin_amdgcn_mfma_f32_32x32x16_bf16(a0l, b0h, c00, 0, 0, 0);
                c01 = __builtin_amdgcn_mfma_f32_32x32x16_bf16(a0h, b1h, c01, 0, 0, 0);
                c01 = __builtin_amdgcn_mfma_f32_32x32x16_bf16(a0h, b1l, c01, 0, 0, 0);
                c01 = __builtin_amdgcn_mfma_f32_32x32x16_bf16(a0l, b1h, c01, 0, 0, 0);
                c10 = __builtin_amdgcn_mfma_f32_32x32x16_bf16(a1h, b0h, c10, 0, 0, 0);
                c10 = __builtin_amdgcn_mfma_f32_32x32x16_bf16(a1h, b0l, c10, 0, 0, 0);
                c10 = __builtin_amdgcn_mfma_f32_32x32x16_bf16(a1l, b0h, c10, 0, 0, 0);
                c11 = __builtin_amdgcn_mfma_f32_32x32x16_bf16(a1h, b1h, c11, 0, 0, 0);
                c11 = __builtin_amdgcn_mfma_f32_32x32x16_bf16(a1h, b1l, c11, 0, 0, 0);
                c11 = __builtin_amdgcn_mfma_f32_32x32x16_bf16(a1l, b1h, c11, 0, 0, 0);
            }
        }
    }

    int colg = x0 + pc;
    int row0 = y0 + pr0 + pr_l;
    int row1 = row0 + 2;
#pragma unroll
    for (int r = 0; r < 16; ++r) {
        int rr = (r & 3) + 8 * (r >> 2) + 4 * kl;
        {
            int co = co_w + rr;
            float bv = biasf[co];
            float* ob = outp + ((size_t)(b * CCH + co)) * HWSZ;
            ob[row0 * 128 + colg] = c00[r] + bv;
            ob[row1 * 128 + colg] = c01[r] + bv;
        }
        {
            int co = co_w + 32 + rr;
            float bv = biasf[co];
            float* ob = outp + ((size_t)(b * CCH + co)) * HWSZ;
            ob[row0 * 128 + colg] = c10[r] + bv;
            ob[row1 * 128 + colg] = c11[r] + bv;
        }
    }
}

// ---------------- fused qkv(MFMA) + window attention, v2: one WG per 8x8 window
// B-frags (x window, tt=wv) in VGPRs; qkvb double-buffered LDS; one barrier/head;
// MFMA(h+1) and attn(h) in the same scheduling region so VALU fills A-load stalls.
__global__ __launch_bounds__(256, 3) void k_attn(const ushort* __restrict__ xhi, const ushort* __restrict__ xlo,
                                                 const ushort* __restrict__ aqh, const ushort* __restrict__ aql,
                                                 const float* __restrict__ bt, float* __restrict__ attnout) {
    __shared__ float qkvb[2][48 * 64];   // 24576 B
    __shared__ float btl[16 * 225];      // 14400 B  (btl[h][rpi])

    int t = threadIdx.x;
    int wv = __builtin_amdgcn_readfirstlane(t >> 6);
    int lane = t & 63;
    int widx = blockIdx.x;
    int b = widx >> 8;
    int rem = widx & 255;
    int hy = rem >> 4, wx = rem & 15;
    int y0 = hy * 8, x0 = wx * 8;

    // ---- stage transposed bias table (one-time)
    for (int i = t; i < 3600; i += 256) {
        int rpi = i >> 4, hh = i & 15;
        btl[hh * 225 + rpi] = bt[i];
    }

    // ---- load this wave's B-fragments (tt = wv) from global into registers
    int tokb = (wv << 4) | (lane & 15);
    int pixb = (y0 + (tokb >> 3)) * 128 + (x0 + (tokb & 7));
    const ushort* xbh = xhi + ((size_t)b * HWSZ + pixb) * 256 + ((lane >> 4) << 3);
    const ushort* xbl = xlo + ((size_t)b * HWSZ + pixb) * 256 + ((lane >> 4) << 3);
    short8v bh_[8], bl_[8];
#pragma unroll
    for (int kk = 0; kk < 8; ++kk) {
        bh_[kk] = *(const short8v*)(xbh + kk * 32);
        bl_[kk] = *(const short8v*)(xbl + kk * 32);
    }

    const short8v* AhB = (const short8v*)aqh + lane;
    const short8v* AlB = (const short8v*)aql + lane;
    int wrow = ((lane >> 4) << 2);            // C-frag row0 within 16
    int wtok = (wv << 4) + (lane & 15);       // C-frag token col

    // ---- head 0 qkv -> buf0
    {
#pragma unroll
        for (int p = 0; p < 3; ++p) {
            f32x4 c = {};
#pragma unroll
            for (int kk = 0; kk < 8; ++kk) {
                short8v ah = AhB[(p * 8 + kk) * 64];
                short8v al = AlB[(p * 8 + kk) * 64];
                c = __builtin_amdgcn_mfma_f32_16x16x32_bf16(ah, bh_[kk], c, 0, 0, 0);
                c = __builtin_amdgcn_mfma_f32_16x16x32_bf16(ah, bl_[kk], c, 0, 0, 0);
                c = __builtin_amdgcn_mfma_f32_16x16x32_bf16(al, bh_[kk], c, 0, 0, 0);
            }
            float* bw = &qkvb[0][(p * 16 + wrow) * 64 + wtok];
            bw[0] = c[0]; bw[64] = c[1]; bw[128] = c[2]; bw[192] = c[3];
        }
    }
    __syncthreads();

    int irow = wv * 16 + (lane & 15);
    int jg = lane >> 4;
    int iy = irow >> 3, ix = irow & 7;

#pragma unroll 2
    for (int h = 0; h < 16; ++h) {
        // ---- qkv MFMA for head (h+1)&15 -> buf (h+1)&1 (redundant at h=15; branch-free)
        int h2 = (h + 1) & 15;
        int nb = (h + 1) & 1;
        const short8v* Ah = AhB + (size_t)h2 * 24 * 64;
        const short8v* Al = AlB + (size_t)h2 * 24 * 64;
#pragma unroll
        for (int p = 0; p < 3; ++p) {
            f32x4 c = {};
#pragma unroll
            for (int kk = 0; kk < 8; ++kk) {
                short8v ah = Ah[(p * 8 + kk) * 64];
                short8v al = Al[(p * 8 + kk) * 64];
                c = __builtin_amdgcn_mfma_f32_16x16x32_bf16(ah, bh_[kk], c, 0, 0, 0);
                c = __builtin_amdgcn_mfma_f32_16x16x32_bf16(ah, bl_[kk], c, 0, 0, 0);
                c = __builtin_amdgcn_mfma_f32_16x16x32_bf16(al, bh_[kk], c, 0, 0, 0);
            }
            float* bw = &qkvb[nb][(p * 16 + wrow) * 64 + wtok];
            bw[0] = c[0]; bw[64] = c[1]; bw[128] = c[2]; bw[192] = c[3];
        }

        // ---- attention for head h from buf h&1 (independent of the MFMA block above)
        const float* buf = qkvb[h & 1];
        float qd[16];
#pragma unroll
        for (int d = 0; d < 16; ++d) qd[d] = buf[d * 64 + irow];
        float s[16];
#pragma unroll
        for (int jj = 0; jj < 16; ++jj) s[jj] = 0.f;
#pragma unroll
        for (int d = 0; d < 16; ++d) {
            const float* kp = &buf[(16 + d) * 64 + jg * 16];
#pragma unroll
            for (int m = 0; m < 4; ++m) {
                float4 kv = *(const float4*)(kp + m * 4);
                s[m * 4 + 0] += qd[d] * kv.x;
                s[m * 4 + 1] += qd[d] * kv.y;
                s[m * 4 + 2] += qd[d] * kv.z;
                s[m * 4 + 3] += qd[d] * kv.w;
            }
        }
#pragma unroll
        for (int jj = 0; jj < 16; ++jj) {
            int j = jg * 16 + jj;
            int jy = j >> 3, jx = j & 7;
            int rpi = (iy - jy + 7) * 15 + (ix - jx + 7);
            s[jj] = s[jj] * 0.25f + btl[h * 225 + rpi];
        }
        float mx = s[0];
#pragma unroll
        for (int jj = 1; jj < 16; ++jj) mx = fmaxf(mx, s[jj]);
        mx = fmaxf(mx, __shfl_xor(mx, 16));
        mx = fmaxf(mx, __shfl_xor(mx, 32));
        float ls = 0.f;
#pragma unroll
        for (int jj = 0; jj < 16; ++jj) { s[jj] = __expf(s[jj] - mx); ls += s[jj]; }
        ls += __shfl_xor(ls, 16);
        ls += __shfl_xor(ls, 32);
        float inv = 1.0f / ls;
#pragma unroll
        for (int d = 0; d < 16; ++d) {
            const float* vp = &buf[(32 + d) * 64 + jg * 16];
            float o0 = 0.f, o1 = 0.f;
#pragma unroll
            for (int m = 0; m < 4; ++m) {
                float4 vvv = *(const float4*)(vp + m * 4);
                o0 += s[m * 4 + 0] * vvv.x + s[m * 4 + 1] * vvv.y;
                o1 += s[m * 4 + 2] * vvv.z + s[m * 4 + 3] * vvv.w;
            }
            float o = o0 + o1;
            o += __shfl_xor(o, 16);
            o += __shfl_xor(o, 32);
            if (jg == 0)
                attnout[((size_t)(b * CCH + h * 16 + d)) * HWSZ + (y0 + iy) * 128 + (x0 + ix)] = o * inv;
        }
        __syncthreads();
    }
}

// ---------------- dual avg-pool + add local
__global__ __launch_bounds__(256) void k_pools(const float* __restrict__ attnout, const float* __restrict__ localb,
                                               float* __restrict__ sbuf) {
    for (int i = blockIdx.x * 256 + threadIdx.x; i < 4 * CCH * HWSZ; i += gridDim.x * 256) {
        int xc = i & 127;
        int y  = (i >> 7) & 127;
        int bc = i >> 14;
        const float* pl = attnout + (size_t)bc * HWSZ;
        float axs = 0.f;
#pragma unroll
        for (int d = -3; d <= 4; ++d) {
            int t2 = y + d;
            if (t2 >= 0 && t2 < 128) axs += pl[t2 * 128 + xc];
        }
        if (y >= 124) axs += pl[126 * 128 + xc];
        float ays = 0.f;
#pragma unroll
        for (int d = -3; d <= 4; ++d) {
            int t2 = xc + d;
            if (t2 >= 0 && t2 < 128) ays += pl[y * 128 + t2];
        }
        if (xc >= 124) ays += pl[y * 128 + 126];
        sbuf[i] = (axs + ays) * 0.125f + localb[i];
    }
}

// ---------------- depthwise 8x8 (reflect +1 pad, zero pad 3) + bn
__device__ __forceinline__ void dw_loadrow(const float* __restrict__ sp, int trow, int j, float* dst) {
    if (trow < 0 || trow > 128) {
#pragma unroll
        for (int q = 0; q < 8; ++q) dst[q] = 0.f;
        return;
    }
    int sr = (trow == 128) ? 126 : trow;
    const float* rp = sp + sr * 128;
#pragma unroll
    for (int q = 0; q < 8; ++q) {
        int col = j - 3 + q;
        float v = 0.f;
        if (col >= 0 && col <= 128) v = rp[(col == 128) ? 126 : col];
        dst[q] = v;
    }
}

__global__ __launch_bounds__(256) void k_dw(const float* __restrict__ sbuf, const float* __restrict__ dww,
                                            const float* __restrict__ pscale, const float* __restrict__ pbias,
                                            float* __restrict__ tbuf) {
    int t = threadIdx.x;
    int j = t & 127;
    int half = __builtin_amdgcn_readfirstlane(t >> 7);
    int bid = blockIdx.x;
    int c = (bid & 127) * 2 + half;
    int b = bid >> 7;
    const float* sp = sbuf + ((size_t)(b * CCH + c)) * HWSZ;
    float wloc[64];
    const float* dwp = dww + c * 64;
#pragma unroll
    for (int i = 0; i < 64; ++i) wloc[i] = dwp[i];
    float scale = pscale[c], bias = pbias[c];

    float rbuf[8][8];
#pragma unroll
    for (int tr = -3; tr <= 4; ++tr) {
        dw_loadrow(sp, tr, j, rbuf[(tr + 8) & 7]);
    }
    float* op = tbuf + ((size_t)(b * CCH + c)) * HWSZ;
    for (int yb = 0; yb < 16; ++yb) {
#pragma unroll
        for (int k = 0; k < 8; ++k) {
            int y = yb * 8 + k;
            float a0 = 0.f, a1 = 0.f, a2 = 0.f, a3 = 0.f;
#pragma unroll
            for (int p = 0; p < 8; ++p) {
                const int slot = (k + 5 + p) & 7;
                float part = 0.f;
#pragma unroll
                for (int q = 0; q < 8; ++q) part += wloc[p * 8 + q] * rbuf[slot][q];
                if ((p & 3) == 0) a0 += part;
                else if ((p & 3) == 1) a1 += part;
                else if ((p & 3) == 2) a2 += part;
                else a3 += part;
            }
            op[y * 128 + j] = scale * ((a0 + a1) + (a2 + a3)) + bias;
            dw_loadrow(sp, y + 5, j, rbuf[(k + 5) & 7]);
        }
    }
}

// ---------------- pointwise 1x1 conv
__global__ __launch_bounds__(256) void k_pw(const float* __restrict__ tbuf, const float* __restrict__ pww,
                                            float* __restrict__ outp) {
    __shared__ __align__(16) float xs[8][128];
    __shared__ __align__(16) float wsm[8][64];
    int t = threadIdx.x;
    int bid = blockIdx.x;
    int cb = bid & 3;
    int row = bid >> 2;
    int y = row & 127;
    int b = row >> 7;
    int cg = t >> 4;
    int px = (t & 15) * 8;
    float acc[4][8];
#pragma unroll
    for (int c = 0; c < 4; ++c)
#pragma unroll
        for (int j = 0; j < 8; ++j) acc[c][j] = 0.f;
    const float* tb = tbuf + (size_t)b * CCH * HWSZ + y * 128;

    for (int cc = 0; cc < 32; ++cc) {
        __syncthreads();
        {
            int i = t;
#pragma unroll
            for (int it = 0; it < 4; ++it, i += 256) {
                int ci = i >> 7, p = i & 127;
                xs[ci][p] = tb[(size_t)(cc * 8 + ci) * HWSZ + p];
            }
        }
        for (int i = t; i < 512; i += 256) {
            int ci = i >> 6, co = i & 63;
            wsm[ci][co] = pww[(size_t)(cb * 64 + co) * 256 + cc * 8 + ci];
        }
        __syncthreads();
#pragma unroll
        for (int ci = 0; ci < 8; ++ci) {
            float4 w = *(const float4*)&wsm[ci][cg * 4];
            float4 xa = *(const float4*)&xs[ci][px];
            float4 xbv = *(const float4*)&xs[ci][px + 4];
            float xf[8] = {xa.x, xa.y, xa.z, xa.w, xbv.x, xbv.y, xbv.z, xbv.w};
#pragma unroll
            for (int j = 0; j < 8; ++j) {
                acc[0][j] += w.x * xf[j];
                acc[1][j] += w.y * xf[j];
                acc[2][j] += w.z * xf[j];
                acc[3][j] += w.w * xf[j];
            }
        }
    }
#pragma unroll
    for (int c = 0; c < 4; ++c) {
        int co = cb * 64 + cg * 4 + c;
        float* op = outp + ((size_t)(b * CCH + co)) * HWSZ + y * 128 + px;
        *(float4*)op = make_float4(acc[c][0], acc[c][1], acc[c][2], acc[c][3]);
        *(float4*)(op + 4) = make_float4(acc[c][4], acc[c][5], acc[c][6], acc[c][7]);
    }
}

extern "C" void kernel_launch(void* const* d_in, const int* in_sizes, int n_in,
                              void* d_out, int out_size, void* d_ws, size_t ws_size,
                              hipStream_t stream) {
    const float* x    = (const float*)d_in[0];
    const float* qkvw = (const float*)d_in[1];
    const float* l1w  = (const float*)d_in[2];
    const float* l1s  = (const float*)d_in[3];
    const float* l1b  = (const float*)d_in[4];
    const float* l2w  = (const float*)d_in[5];
    const float* l2s  = (const float*)d_in[6];
    const float* l2b  = (const float*)d_in[7];
    const float* dww  = (const float*)d_in[8];
    const float* ps   = (const float*)d_in[9];
    const float* pb   = (const float*)d_in[10];
    const float* pww  = (const float*)d_in[11];
    const float* bt   = (const float*)d_in[12];
    float* out = (float*)d_out;
    float* wsf = (float*)d_ws;

    const size_t nWf = 589824;          // 2304*256
    const size_t nPlane = 16777216;     // 4*256*128*128
    const size_t nAq = 196608;          // 16*3*8*64*8
    size_t need = (nWf + 256 + 3 * nPlane) * sizeof(float) + (2 * 589824 + 2 * nAq) * sizeof(ushort);
    if (ws_size < need) return;

    float* Wf      = wsf;
    float* biasf   = wsf + nWf;
    float* attnout = wsf + nWf + 256;
    float* localb  = attnout + nPlane;
    float* sbuf    = localb + nPlane;
    float* tbuf    = attnout;                 // attnout dead after k_pools
    ushort* xhi = (ushort*)sbuf;              // aliases sbuf (dead until k_pools)
    ushort* xlo = xhi + nPlane;
    ushort* ahi = (ushort*)(sbuf + nPlane);   // after sbuf region
    ushort* alo = ahi + 589824;
    ushort* aqh = alo + 589824;
    ushort* aql = aqh + nAq;

    k_fold  <<<2304, 256, 0, stream>>>(l1w, l1s, l1b, l2w, l2s, l2b, Wf, biasf);
    k_wsplit<<<2304, 256, 0, stream>>>(Wf, ahi, alo);
    k_aswz  <<<768,  256, 0, stream>>>(qkvw, aqh, aql);
    k_cvt   <<<2048, 256, 0, stream>>>(x, xhi, xlo);
    k_conv3m<<<1024, 256, 0, stream>>>(xhi, xlo, ahi, alo, biasf, localb);
    k_attn  <<<1024, 256, 0, stream>>>(xhi, xlo, aqh, aql, bt, attnout);
    k_pools <<<4096, 256, 0, stream>>>(attnout, localb, sbuf);
    k_dw    <<<512,  256, 0, stream>>>(sbuf, dww, ps, pb, tbuf);
    k_pw    <<<2048, 256, 0, stream>>>(tbuf, pww, out);
}

// Round 7
// 877.167 us; speedup vs baseline: 3.6288x; 1.0081x over previous
//
#include <hip/hip_runtime.h>
#include <cstddef>

#define HH 128
#define WW2 128
#define HWSZ (HH*WW2)
#define CCH 256

typedef __attribute__((ext_vector_type(8))) short short8v;   // 8 bf16 = 4 VGPR
typedef __attribute__((ext_vector_type(16))) float f32x16;   // MFMA 32x32 acc
typedef __attribute__((ext_vector_type(4)))  float f32x4;    // MFMA 16x16 acc

__device__ __forceinline__ ushort bf16rte(float v) {
    uint u = __float_as_uint(v);
    uint r = u + 0x7FFFu + ((u >> 16) & 1u);
    return (ushort)(r >> 16);
}

// ---------------- fold: Wf[ci*9+k][co] = l1s*l1w (+ center: l2s*l2w); biasf = l1b+l2b
__global__ __launch_bounds__(256) void k_fold(const float* __restrict__ l1w, const float* __restrict__ l1s,
                                              const float* __restrict__ l1b, const float* __restrict__ l2w,
                                              const float* __restrict__ l2s, const float* __restrict__ l2b,
                                              float* __restrict__ Wf, float* __restrict__ biasf) {
    int idx = blockIdx.x * 256 + threadIdx.x;
    if (idx < 2304 * 256) {
        int co = idx & 255;
        int i2 = idx >> 8;           // 0..2303 = ci*9+k
        int ci = i2 / 9;
        int k  = i2 - ci * 9;
        float w = l1s[co] * l1w[co * 2304 + ci * 9 + k];
        if (k == 4) w += l2s[co] * l2w[co * 256 + ci];
        Wf[i2 * 256 + co] = w;
    }
    if (idx < 256) biasf[idx] = l1b[idx] + l2b[idx];
}

// ---------------- conv weight split into 32x32 A-fragment order, hi/lo bf16 planes
__global__ __launch_bounds__(256) void k_wsplit(const float* __restrict__ Wf,
                                                ushort* __restrict__ ahi, ushort* __restrict__ alo) {
    int idx = blockIdx.x * 256 + threadIdx.x;     // 589824 total
    if (idx >= 589824) return;
    int j    = idx & 7;
    int lane = (idx >> 3) & 63;
    int t2   = idx >> 9;
    int kb   = t2 % 144;
    int cob  = t2 / 144;
    int cc  = kb / 18; int rem = kb - cc * 18; int tap = rem >> 1; int ks = rem & 1;
    int ci  = cc * 32 + ks * 16 + ((lane >> 5) << 3) + j;
    int co  = cob * 32 + (lane & 31);
    float v = Wf[(size_t)(ci * 9 + tap) * 256 + co];
    ushort h = bf16rte(v);
    float hf = __uint_as_float((uint)h << 16);
    ushort l = bf16rte(v - hf);
    ahi[idx] = h;
    alo[idx] = l;
}

// ---------------- qkv weight split into 16x16x32 A-fragment order, hi/lo planes
// layout: [(h*3+p)*8+kk][lane][8j]; co = p*256+h*16+(lane&15); ci = kk*32+(lane>>4)*8+j
__global__ __launch_bounds__(256) void k_aswz(const float* __restrict__ qkvw,
                                              ushort* __restrict__ aqh, ushort* __restrict__ aql) {
    int idx = blockIdx.x * 256 + threadIdx.x;     // 196608 total
    if (idx >= 196608) return;
    int j    = idx & 7;
    int lane = (idx >> 3) & 63;
    int t2   = idx >> 9;          // 0..383 = (h*3+p)*8+kk
    int kk   = t2 & 7;
    int hp   = t2 >> 3;           // h*3+p
    int p    = hp % 3, h = hp / 3;
    int co = p * 256 + h * 16 + (lane & 15);
    int ci = kk * 32 + ((lane >> 4) << 3) + j;
    float v = qkvw[(size_t)co * 256 + ci];
    ushort hi = bf16rte(v);
    float hf = __uint_as_float((uint)hi << 16);
    aqh[idx] = hi;
    aql[idx] = bf16rte(v - hf);
}

// ---------------- x -> pixel-major bf16 hi/lo planes: xT[b][pix][256ci]
__global__ __launch_bounds__(256) void k_cvt(const float* __restrict__ x,
                                             ushort* __restrict__ xhi, ushort* __restrict__ xlo) {
    __shared__ uint pk[32 * 265];
    int t = threadIdx.x;
    int bid = blockIdx.x;               // 4 * 512
    int b = bid >> 9;
    int px0 = (bid & 511) * 32;
    const float* xb = x + (size_t)b * CCH * HWSZ;
    for (int step = 0; step < 32; ++step) {
        int ci = step * 8 + (t >> 5);
        float v = xb[(size_t)ci * HWSZ + px0 + (t & 31)];
        ushort h = bf16rte(v);
        float hf = __uint_as_float((uint)h << 16);
        ushort l = bf16rte(v - hf);
        pk[(t & 31) * 265 + ci] = ((uint)h << 16) | l;
    }
    __syncthreads();
    int pxl = t >> 3, o = t & 7;
    uint* hp = (uint*)xhi;
    uint* lp = (uint*)xlo;
    size_t pb2 = ((size_t)b * HWSZ + px0 + pxl) * 128;
#pragma unroll
    for (int m = 0; m < 16; ++m) {
        int cip = m * 16 + o * 2;
        uint p0 = pk[pxl * 265 + cip];
        uint p1 = pk[pxl * 265 + cip + 1];
        hp[pb2 + m * 8 + o] = (p1 & 0xFFFF0000u) | (p0 >> 16);
        lp[pb2 + m * 8 + o] = (p1 << 16) | (p0 & 0xFFFFu);
    }
}

// ---------------- conv3x3 as implicit GEMM via mfma_f32_32x32x16_bf16 (3-term split)
// v2: double-buffered LDS, issue-early/write-late staging, 1 barrier/chunk, XCD swizzle
__global__ __launch_bounds__(256) void k_conv3m(const ushort* __restrict__ xhi, const ushort* __restrict__ xlo,
                                                const ushort* __restrict__ afr_hi, const ushort* __restrict__ afr_lo,
                                                const float* __restrict__ biasf, float* __restrict__ outp) {
    __shared__ __align__(16) ushort Xsh[25920];   // 2 bufs x (hi 12960B + lo 12960B)
    char* xsb = (char*)Xsh;

    int t = threadIdx.x;
    // bijective XCD swizzle for grid=1024: 8 XCDs x 128 consecutive work ids
    int orig = blockIdx.x;
    int bid = (orig & 7) * 128 + (orig >> 3);
    int cb = bid & 1;
    int t2 = bid >> 1;
    int tile_c = t2 & 7;
    int tile_r = (t2 >> 3) & 15;
    int b = t2 >> 7;
    int x0 = tile_c * 16, y0 = tile_r * 8;

    int w = t >> 6, lane = t & 63;
    int co_w = cb * 128 + (w >> 1) * 64;
    int pr0 = (w & 1) * 4;
    int pr_l = (lane & 31) >> 4;
    int pc = lane & 15;
    int kl = lane >> 5;
    int lb0 = (pr0 + 0 + pr_l) * 1296 + pc * 72 + kl * 16;
    int lb1 = (pr0 + 2 + pr_l) * 1296 + pc * 72 + kl * 16;

    const short8v* Ahi = (const short8v*)afr_hi;
    const short8v* Alo = (const short8v*)afr_lo;
    int cobase = (co_w >> 5) * 144 * 64;

    f32x16 c00 = {}, c01 = {}, c10 = {}, c11 = {};

    // staged regs for next chunk
    uint4 st[6];

    // issue global loads for chunk cc into st[]
    auto stage_issue = [&](int cc) {
#pragma unroll
        for (int it = 0; it < 6; ++it) {
            int i = t + it * 256;
            uint4 v = make_uint4(0u, 0u, 0u, 0u);
            if (i < 1440) {
                int oct = i & 3;
                int j2 = i >> 2;
                int plane = j2 & 1;
                int loc = j2 >> 1;
                int r = loc / 18, c = loc - r * 18;
                int gy = y0 - 1 + r, gx = x0 - 1 + c;
                if (gy >= 0 && gy < 128 && gx >= 0 && gx < 128) {
                    const ushort* src = plane ? xlo : xhi;
                    v = *(const uint4*)(src + ((size_t)(b * HWSZ + gy * 128 + gx) * 256 + cc * 32 + oct * 8));
                }
            }
            st[it] = v;
        }
    };
    // write staged regs into LDS buffer `buf`
    auto stage_write = [&](int buf) {
#pragma unroll
        for (int it = 0; it < 6; ++it) {
            int i = t + it * 256;
            if (i < 1440) {
                int oct = i & 3;
                int j2 = i >> 2;
                int plane = j2 & 1;
                int loc = j2 >> 1;
                *(uint4*)(xsb + buf * 25920 + plane * 12960 + loc * 72 + oct * 16) = st[it];
            }
        }
    };

    // prologue: stage chunk 0 into buf 0
    stage_issue(0);
    stage_write(0);

    for (int cc = 0; cc < 8; ++cc) {
        if (cc < 7) stage_issue(cc + 1);      // loads in flight over the MFMA block
        __syncthreads();                      // writes to buf[cc&1] visible
        int bufoff = (cc & 1) * 25920;

        int baseA = cobase + cc * 18 * 64 + lane;
#pragma unroll
        for (int tap = 0; tap < 9; ++tap) {
            const int ky = tap / 3, kx = tap - ky * 3;
#pragma unroll
            for (int ks = 0; ks < 2; ++ks) {
                const int boff = bufoff + ky * 1296 + kx * 72 + ks * 32;
                short8v b0h = *(const short8v*)(xsb + lb0 + boff);
                short8v b0l = *(const short8v*)(xsb + lb0 + boff + 12960);
                short8v b1h = *(const short8v*)(xsb + lb1 + boff);
                short8v b1l = *(const short8v*)(xsb + lb1 + boff + 12960);
                int ai = baseA + (tap * 2 + ks) * 64;
                short8v a0h = Ahi[ai];
                short8v a0l = Alo[ai];
                short8v a1h = Ahi[ai + 144 * 64];
                short8v a1l = Alo[ai + 144 * 64];
                c00 = __builtin_amdgcn_mfma_f32_32x32x16_bf16(a0h, b0h, c00, 0, 0, 0);
                c00 = __builtin_amdgcn_mfma_f32_32x32x16_bf16(a0h, b0l, c00, 0, 0, 0);
                c00 = __builtin_amdgcn_mfma_f32_32x32x16_bf16(a0l, b0h, c00, 0, 0, 0);
                c01 = __builtin_amdgcn_mfma_f32_32x32x16_bf16(a0h, b1h, c01, 0, 0, 0);
                c01 = __builtin_amdgcn_mfma_f32_32x32x16_bf16(a0h, b1l, c01, 0, 0, 0);
                c01 = __builtin_amdgcn_mfma_f32_32x32x16_bf16(a0l, b1h, c01, 0, 0, 0);
                c10 = __builtin_amdgcn_mfma_f32_32x32x16_bf16(a1h, b0h, c10, 0, 0, 0);
                c10 = __builtin_amdgcn_mfma_f32_32x32x16_bf16(a1h, b0l, c10, 0, 0, 0);
                c10 = __builtin_amdgcn_mfma_f32_32x32x16_bf16(a1l, b0h, c10, 0, 0, 0);
                c11 = __builtin_amdgcn_mfma_f32_32x32x16_bf16(a1h, b1h, c11, 0, 0, 0);
                c11 = __builtin_amdgcn_mfma_f32_32x32x16_bf16(a1h, b1l, c11, 0, 0, 0);
                c11 = __builtin_amdgcn_mfma_f32_32x32x16_bf16(a1l, b1h, c11, 0, 0, 0);
            }
        }
        // write next chunk into the other buffer; readers of that buffer finished
        // before this iteration's top barrier.
        if (cc < 7) stage_write((cc + 1) & 1);
    }

    int colg = x0 + pc;
    int row0 = y0 + pr0 + pr_l;
    int row1 = row0 + 2;
#pragma unroll
    for (int r = 0; r < 16; ++r) {
        int rr = (r & 3) + 8 * (r >> 2) + 4 * kl;
        {
            int co = co_w + rr;
            float bv = biasf[co];
            float* ob = outp + ((size_t)(b * CCH + co)) * HWSZ;
            ob[row0 * 128 + colg] = c00[r] + bv;
            ob[row1 * 128 + colg] = c01[r] + bv;
        }
        {
            int co = co_w + 32 + rr;
            float bv = biasf[co];
            float* ob = outp + ((size_t)(b * CCH + co)) * HWSZ;
            ob[row0 * 128 + colg] = c10[r] + bv;
            ob[row1 * 128 + colg] = c11[r] + bv;
        }
    }
}

// ---------------- fused qkv(MFMA) + window attention, v2: one WG per 8x8 window
__global__ __launch_bounds__(256, 3) void k_attn(const ushort* __restrict__ xhi, const ushort* __restrict__ xlo,
                                                 const ushort* __restrict__ aqh, const ushort* __restrict__ aql,
                                                 const float* __restrict__ bt, float* __restrict__ attnout) {
    __shared__ float qkvb[2][48 * 64];   // 24576 B
    __shared__ float btl[16 * 225];      // 14400 B  (btl[h][rpi])

    int t = threadIdx.x;
    int wv = __builtin_amdgcn_readfirstlane(t >> 6);
    int lane = t & 63;
    int widx = blockIdx.x;
    int b = widx >> 8;
    int rem = widx & 255;
    int hy = rem >> 4, wx = rem & 15;
    int y0 = hy * 8, x0 = wx * 8;

    // ---- stage transposed bias table (one-time)
    for (int i = t; i < 3600; i += 256) {
        int rpi = i >> 4, hh = i & 15;
        btl[hh * 225 + rpi] = bt[i];
    }

    // ---- load this wave's B-fragments (tt = wv) from global into registers
    int tokb = (wv << 4) | (lane & 15);
    int pixb = (y0 + (tokb >> 3)) * 128 + (x0 + (tokb & 7));
    const ushort* xbh = xhi + ((size_t)b * HWSZ + pixb) * 256 + ((lane >> 4) << 3);
    const ushort* xbl = xlo + ((size_t)b * HWSZ + pixb) * 256 + ((lane >> 4) << 3);
    short8v bh_[8], bl_[8];
#pragma unroll
    for (int kk = 0; kk < 8; ++kk) {
        bh_[kk] = *(const short8v*)(xbh + kk * 32);
        bl_[kk] = *(const short8v*)(xbl + kk * 32);
    }

    const short8v* AhB = (const short8v*)aqh + lane;
    const short8v* AlB = (const short8v*)aql + lane;
    int wrow = ((lane >> 4) << 2);            // C-frag row0 within 16
    int wtok = (wv << 4) + (lane & 15);       // C-frag token col

    // ---- head 0 qkv -> buf0
    {
#pragma unroll
        for (int p = 0; p < 3; ++p) {
            f32x4 c = {};
#pragma unroll
            for (int kk = 0; kk < 8; ++kk) {
                short8v ah = AhB[(p * 8 + kk) * 64];
                short8v al = AlB[(p * 8 + kk) * 64];
                c = __builtin_amdgcn_mfma_f32_16x16x32_bf16(ah, bh_[kk], c, 0, 0, 0);
                c = __builtin_amdgcn_mfma_f32_16x16x32_bf16(ah, bl_[kk], c, 0, 0, 0);
                c = __builtin_amdgcn_mfma_f32_16x16x32_bf16(al, bh_[kk], c, 0, 0, 0);
            }
            float* bw = &qkvb[0][(p * 16 + wrow) * 64 + wtok];
            bw[0] = c[0]; bw[64] = c[1]; bw[128] = c[2]; bw[192] = c[3];
        }
    }
    __syncthreads();

    int irow = wv * 16 + (lane & 15);
    int jg = lane >> 4;
    int iy = irow >> 3, ix = irow & 7;

#pragma unroll 2
    for (int h = 0; h < 16; ++h) {
        // ---- qkv MFMA for head (h+1)&15 -> buf (h+1)&1 (redundant at h=15; branch-free)
        int h2 = (h + 1) & 15;
        int nb = (h + 1) & 1;
        const short8v* Ah = AhB + (size_t)h2 * 24 * 64;
        const short8v* Al = AlB + (size_t)h2 * 24 * 64;
#pragma unroll
        for (int p = 0; p < 3; ++p) {
            f32x4 c = {};
#pragma unroll
            for (int kk = 0; kk < 8; ++kk) {
                short8v ah = Ah[(p * 8 + kk) * 64];
                short8v al = Al[(p * 8 + kk) * 64];
                c = __builtin_amdgcn_mfma_f32_16x16x32_bf16(ah, bh_[kk], c, 0, 0, 0);
                c = __builtin_amdgcn_mfma_f32_16x16x32_bf16(ah, bl_[kk], c, 0, 0, 0);
                c = __builtin_amdgcn_mfma_f32_16x16x32_bf16(al, bh_[kk], c, 0, 0, 0);
            }
            float* bw = &qkvb[nb][(p * 16 + wrow) * 64 + wtok];
            bw[0] = c[0]; bw[64] = c[1]; bw[128] = c[2]; bw[192] = c[3];
        }

        // ---- attention for head h from buf h&1 (independent of the MFMA block above)
        const float* buf = qkvb[h & 1];
        float qd[16];
#pragma unroll
        for (int d = 0; d < 16; ++d) qd[d] = buf[d * 64 + irow];
        float s[16];
#pragma unroll
        for (int jj = 0; jj < 16; ++jj) s[jj] = 0.f;
#pragma unroll
        for (int d = 0; d < 16; ++d) {
            const float* kp = &buf[(16 + d) * 64 + jg * 16];
#pragma unroll
            for (int m = 0; m < 4; ++m) {
                float4 kv = *(const float4*)(kp + m * 4);
                s[m * 4 + 0] += qd[d] * kv.x;
                s[m * 4 + 1] += qd[d] * kv.y;
                s[m * 4 + 2] += qd[d] * kv.z;
                s[m * 4 + 3] += qd[d] * kv.w;
            }
        }
#pragma unroll
        for (int jj = 0; jj < 16; ++jj) {
            int j = jg * 16 + jj;
            int jy = j >> 3, jx = j & 7;
            int rpi = (iy - jy + 7) * 15 + (ix - jx + 7);
            s[jj] = s[jj] * 0.25f + btl[h * 225 + rpi];
        }
        float mx = s[0];
#pragma unroll
        for (int jj = 1; jj < 16; ++jj) mx = fmaxf(mx, s[jj]);
        mx = fmaxf(mx, __shfl_xor(mx, 16));
        mx = fmaxf(mx, __shfl_xor(mx, 32));
        float ls = 0.f;
#pragma unroll
        for (int jj = 0; jj < 16; ++jj) { s[jj] = __expf(s[jj] - mx); ls += s[jj]; }
        ls += __shfl_xor(ls, 16);
        ls += __shfl_xor(ls, 32);
        float inv = 1.0f / ls;
#pragma unroll
        for (int d = 0; d < 16; ++d) {
            const float* vp = &buf[(32 + d) * 64 + jg * 16];
            float o0 = 0.f, o1 = 0.f;
#pragma unroll
            for (int m = 0; m < 4; ++m) {
                float4 vvv = *(const float4*)(vp + m * 4);
                o0 += s[m * 4 + 0] * vvv.x + s[m * 4 + 1] * vvv.y;
                o1 += s[m * 4 + 2] * vvv.z + s[m * 4 + 3] * vvv.w;
            }
            float o = o0 + o1;
            o += __shfl_xor(o, 16);
            o += __shfl_xor(o, 32);
            if (jg == 0)
                attnout[((size_t)(b * CCH + h * 16 + d)) * HWSZ + (y0 + iy) * 128 + (x0 + ix)] = o * inv;
        }
        __syncthreads();
    }
}

// ---------------- dual avg-pool + add local
__global__ __launch_bounds__(256) void k_pools(const float* __restrict__ attnout, const float* __restrict__ localb,
                                               float* __restrict__ sbuf) {
    for (int i = blockIdx.x * 256 + threadIdx.x; i < 4 * CCH * HWSZ; i += gridDim.x * 256) {
        int xc = i & 127;
        int y  = (i >> 7) & 127;
        int bc = i >> 14;
        const float* pl = attnout + (size_t)bc * HWSZ;
        float axs = 0.f;
#pragma unroll
        for (int d = -3; d <= 4; ++d) {
            int t2 = y + d;
            if (t2 >= 0 && t2 < 128) axs += pl[t2 * 128 + xc];
        }
        if (y >= 124) axs += pl[126 * 128 + xc];
        float ays = 0.f;
#pragma unroll
        for (int d = -3; d <= 4; ++d) {
            int t2 = xc + d;
            if (t2 >= 0 && t2 < 128) ays += pl[y * 128 + t2];
        }
        if (xc >= 124) ays += pl[y * 128 + 126];
        sbuf[i] = (axs + ays) * 0.125f + localb[i];
    }
}

// ---------------- depthwise 8x8 (reflect +1 pad, zero pad 3) + bn
__device__ __forceinline__ void dw_loadrow(const float* __restrict__ sp, int trow, int j, float* dst) {
    if (trow < 0 || trow > 128) {
#pragma unroll
        for (int q = 0; q < 8; ++q) dst[q] = 0.f;
        return;
    }
    int sr = (trow == 128) ? 126 : trow;
    const float* rp = sp + sr * 128;
#pragma unroll
    for (int q = 0; q < 8; ++q) {
        int col = j - 3 + q;
        float v = 0.f;
        if (col >= 0 && col <= 128) v = rp[(col == 128) ? 126 : col];
        dst[q] = v;
    }
}

__global__ __launch_bounds__(256) void k_dw(const float* __restrict__ sbuf, const float* __restrict__ dww,
                                            const float* __restrict__ pscale, const float* __restrict__ pbias,
                                            float* __restrict__ tbuf) {
    int t = threadIdx.x;
    int j = t & 127;
    int half = __builtin_amdgcn_readfirstlane(t >> 7);
    int bid = blockIdx.x;
    int c = (bid & 127) * 2 + half;
    int b = bid >> 7;
    const float* sp = sbuf + ((size_t)(b * CCH + c)) * HWSZ;
    float wloc[64];
    const float* dwp = dww + c * 64;
#pragma unroll
    for (int i = 0; i < 64; ++i) wloc[i] = dwp[i];
    float scale = pscale[c], bias = pbias[c];

    float rbuf[8][8];
#pragma unroll
    for (int tr = -3; tr <= 4; ++tr) {
        dw_loadrow(sp, tr, j, rbuf[(tr + 8) & 7]);
    }
    float* op = tbuf + ((size_t)(b * CCH + c)) * HWSZ;
    for (int yb = 0; yb < 16; ++yb) {
#pragma unroll
        for (int k = 0; k < 8; ++k) {
            int y = yb * 8 + k;
            float a0 = 0.f, a1 = 0.f, a2 = 0.f, a3 = 0.f;
#pragma unroll
            for (int p = 0; p < 8; ++p) {
                const int slot = (k + 5 + p) & 7;
                float part = 0.f;
#pragma unroll
                for (int q = 0; q < 8; ++q) part += wloc[p * 8 + q] * rbuf[slot][q];
                if ((p & 3) == 0) a0 += part;
                else if ((p & 3) == 1) a1 += part;
                else if ((p & 3) == 2) a2 += part;
                else a3 += part;
            }
            op[y * 128 + j] = scale * ((a0 + a1) + (a2 + a3)) + bias;
            dw_loadrow(sp, y + 5, j, rbuf[(k + 5) & 7]);
        }
    }
}

// ---------------- pointwise 1x1 conv
__global__ __launch_bounds__(256) void k_pw(const float* __restrict__ tbuf, const float* __restrict__ pww,
                                            float* __restrict__ outp) {
    __shared__ __align__(16) float xs[8][128];
    __shared__ __align__(16) float wsm[8][64];
    int t = threadIdx.x;
    int bid = blockIdx.x;
    int cb = bid & 3;
    int row = bid >> 2;
    int y = row & 127;
    int b = row >> 7;
    int cg = t >> 4;
    int px = (t & 15) * 8;
    float acc[4][8];
#pragma unroll
    for (int c = 0; c < 4; ++c)
#pragma unroll
        for (int j = 0; j < 8; ++j) acc[c][j] = 0.f;
    const float* tb = tbuf + (size_t)b * CCH * HWSZ + y * 128;

    for (int cc = 0; cc < 32; ++cc) {
        __syncthreads();
        {
            int i = t;
#pragma unroll
            for (int it = 0; it < 4; ++it, i += 256) {
                int ci = i >> 7, p = i & 127;
                xs[ci][p] = tb[(size_t)(cc * 8 + ci) * HWSZ + p];
            }
        }
        for (int i = t; i < 512; i += 256) {
            int ci = i >> 6, co = i & 63;
            wsm[ci][co] = pww[(size_t)(cb * 64 + co) * 256 + cc * 8 + ci];
        }
        __syncthreads();
#pragma unroll
        for (int ci = 0; ci < 8; ++ci) {
            float4 w = *(const float4*)&wsm[ci][cg * 4];
            float4 xa = *(const float4*)&xs[ci][px];
            float4 xbv = *(const float4*)&xs[ci][px + 4];
            float xf[8] = {xa.x, xa.y, xa.z, xa.w, xbv.x, xbv.y, xbv.z, xbv.w};
#pragma unroll
            for (int j = 0; j < 8; ++j) {
                acc[0][j] += w.x * xf[j];
                acc[1][j] += w.y * xf[j];
                acc[2][j] += w.z * xf[j];
                acc[3][j] += w.w * xf[j];
            }
        }
    }
#pragma unroll
    for (int c = 0; c < 4; ++c) {
        int co = cb * 64 + cg * 4 + c;
        float* op = outp + ((size_t)(b * CCH + co)) * HWSZ + y * 128 + px;
        *(float4*)op = make_float4(acc[c][0], acc[c][1], acc[c][2], acc[c][3]);
        *(float4*)(op + 4) = make_float4(acc[c][4], acc[c][5], acc[c][6], acc[c][7]);
    }
}

extern "C" void kernel_launch(void* const* d_in, const int* in_sizes, int n_in,
                              void* d_out, int out_size, void* d_ws, size_t ws_size,
                              hipStream_t stream) {
    const float* x    = (const float*)d_in[0];
    const float* qkvw = (const float*)d_in[1];
    const float* l1w  = (const float*)d_in[2];
    const float* l1s  = (const float*)d_in[3];
    const float* l1b  = (const float*)d_in[4];
    const float* l2w  = (const float*)d_in[5];
    const float* l2s  = (const float*)d_in[6];
    const float* l2b  = (const float*)d_in[7];
    const float* dww  = (const float*)d_in[8];
    const float* ps   = (const float*)d_in[9];
    const float* pb   = (const float*)d_in[10];
    const float* pww  = (const float*)d_in[11];
    const float* bt   = (const float*)d_in[12];
    float* out = (float*)d_out;
    float* wsf = (float*)d_ws;

    const size_t nWf = 589824;          // 2304*256
    const size_t nPlane = 16777216;     // 4*256*128*128
    const size_t nAq = 196608;          // 16*3*8*64*8
    size_t need = (nWf + 256 + 3 * nPlane) * sizeof(float) + (2 * 589824 + 2 * nAq) * sizeof(ushort);
    if (ws_size < need) return;

    float* Wf      = wsf;
    float* biasf   = wsf + nWf;
    float* attnout = wsf + nWf + 256;
    float* localb  = attnout + nPlane;
    float* sbuf    = localb + nPlane;
    float* tbuf    = attnout;                 // attnout dead after k_pools
    ushort* xhi = (ushort*)sbuf;              // aliases sbuf (dead until k_pools)
    ushort* xlo = xhi + nPlane;
    ushort* ahi = (ushort*)(sbuf + nPlane);   // after sbuf region
    ushort* alo = ahi + 589824;
    ushort* aqh = alo + 589824;
    ushort* aql = aqh + nAq;

    k_fold  <<<2304, 256, 0, stream>>>(l1w, l1s, l1b, l2w, l2s, l2b, Wf, biasf);
    k_wsplit<<<2304, 256, 0, stream>>>(Wf, ahi, alo);
    k_aswz  <<<768,  256, 0, stream>>>(qkvw, aqh, aql);
    k_cvt   <<<2048, 256, 0, stream>>>(x, xhi, xlo);
    k_conv3m<<<1024, 256, 0, stream>>>(xhi, xlo, ahi, alo, biasf, localb);
    k_attn  <<<1024, 256, 0, stream>>>(xhi, xlo, aqh, aql, bt, attnout);
    k_pools <<<4096, 256, 0, stream>>>(attnout, localb, sbuf);
    k_dw    <<<512,  256, 0, stream>>>(sbuf, dww, ps, pb, tbuf);
    k_pw    <<<2048, 256, 0, stream>>>(tbuf, pww, out);
}